// Round 2
// baseline (3558.243 us; speedup 1.0000x reference)
//
#include <hip/hip_runtime.h>
#include <math.h>

// Problem constants
#define NROW 8192   // B*T
#define DIM  512
#define TT   2048
#define HH   4
#define DH   128
#define GG   2025   // GH*GW
#define SS   2048
#define KTOP 40

// ---------------------------------------------------------------------------
// embed gather + layernorm:  x = table[tok], xn = LN(x)*g + b
// ---------------------------------------------------------------------------
__global__ __launch_bounds__(256) void k_embed_ln(
    const int* __restrict__ tokens, const float* __restrict__ table,
    const float* __restrict__ g, const float* __restrict__ b,
    float* __restrict__ x, float* __restrict__ xn)
{
    __shared__ float red[4];
    const int row = blockIdx.x;
    const int tid = threadIdx.x;
    const float* src = table + (size_t)tokens[row] * DIM;
    float v0 = src[tid], v1 = src[tid + 256];

    float s = v0 + v1;
    for (int off = 32; off; off >>= 1) s += __shfl_xor(s, off, 64);
    if ((tid & 63) == 0) red[tid >> 6] = s;
    __syncthreads();
    float mean = (red[0] + red[1] + red[2] + red[3]) * (1.0f / 512.0f);
    __syncthreads();

    float d0 = v0 - mean, d1 = v1 - mean;
    float ss = d0 * d0 + d1 * d1;
    for (int off = 32; off; off >>= 1) ss += __shfl_xor(ss, off, 64);
    if ((tid & 63) == 0) red[tid >> 6] = ss;
    __syncthreads();
    float var = (red[0] + red[1] + red[2] + red[3]) * (1.0f / 512.0f);
    float rs = 1.0f / sqrtf(var + 1e-5f);

    size_t base = (size_t)row * DIM;
    x[base + tid]        = v0;
    x[base + tid + 256]  = v1;
    xn[base + tid]       = d0 * rs * g[tid] + b[tid];
    xn[base + tid + 256] = d1 * rs * g[tid + 256] + b[tid + 256];
}

// ---------------------------------------------------------------------------
// generic GEMM  C = epi(A @ B + bias); ACC = float or double accumulator.
// A: MxK row-major, B: KxN row-major. 64x64 tile, BK=16, 256 thr, 4x4/thread.
// ---------------------------------------------------------------------------
enum { EPI_BIAS = 0, EPI_SIGMOID = 1, EPI_GATERES = 2, EPI_GELU = 3, EPI_NONE = 4 };

template<int EPI, typename ACC>
__global__ __launch_bounds__(256) void k_gemm(
    const float* __restrict__ A, const float* __restrict__ B,
    const float* __restrict__ bias, float* __restrict__ C,
    int M, int N, int K,
    const float* __restrict__ resid, const float* __restrict__ gate)
{
    __shared__ float As[16][68];
    __shared__ float Bs[16][64];
    const int tid = threadIdx.x;
    const int tx = tid & 15, ty = tid >> 4;
    const int bm = blockIdx.y * 64, bn = blockIdx.x * 64;
    ACC acc[4][4] = {};

    const int la_k = tid & 15, la_m = tid >> 4;
    const int lb_n = tid & 63, lb_k = tid >> 6;

    for (int k0 = 0; k0 < K; k0 += 16) {
#pragma unroll
        for (int i = 0; i < 4; ++i) {
            int m = bm + la_m + 16 * i, k = k0 + la_k;
            As[la_k][la_m + 16 * i] = (m < M && k < K) ? A[(size_t)m * K + k] : 0.0f;
        }
#pragma unroll
        for (int i = 0; i < 4; ++i) {
            int k = k0 + lb_k + 4 * i;
            Bs[lb_k + 4 * i][lb_n] = (k < K && bn + lb_n < N) ? B[(size_t)k * N + bn + lb_n] : 0.0f;
        }
        __syncthreads();
#pragma unroll
        for (int kk = 0; kk < 16; ++kk) {
            float4 a4 = *(const float4*)&As[kk][ty * 4];
            float4 b4 = *(const float4*)&Bs[kk][tx * 4];
            float av[4] = {a4.x, a4.y, a4.z, a4.w};
            float bv[4] = {b4.x, b4.y, b4.z, b4.w};
#pragma unroll
            for (int i = 0; i < 4; ++i)
#pragma unroll
                for (int j = 0; j < 4; ++j)
                    acc[i][j] = fma((ACC)av[i], (ACC)bv[j], acc[i][j]);
        }
        __syncthreads();
    }

#pragma unroll
    for (int i = 0; i < 4; ++i) {
        int m = bm + ty * 4 + i;
        if (m >= M) continue;
#pragma unroll
        for (int j = 0; j < 4; ++j) {
            int n = bn + tx * 4 + j;
            if (n >= N) continue;
            size_t idx = (size_t)m * N + n;
            float t = (float)acc[i][j];
            if (EPI != EPI_NONE) t += bias[n];
            float r;
            if (EPI == EPI_SIGMOID)      r = 1.0f / (1.0f + expf(-t));
            else if (EPI == EPI_GATERES) r = resid[idx] + gate[idx] * t;
            else if (EPI == EPI_GELU)    r = 0.5f * t * (1.0f + erff(t * 0.70710678118654752440f));
            else                         r = t;
            C[idx] = r;
        }
    }
}

// ---------------------------------------------------------------------------
// banded attention, window half-width 5 (W=11). One wave per (b,t,h).
// ---------------------------------------------------------------------------
__global__ __launch_bounds__(256) void k_attn(
    const float* __restrict__ q, const float* __restrict__ k,
    const float* __restrict__ v, float* __restrict__ out)
{
    const int w    = (blockIdx.x << 2) + (threadIdx.x >> 6);
    const int lane = threadIdx.x & 63;
    const int h = w & 3;
    const int t = (w >> 2) & 2047;
    const int b = w >> 13;
    const size_t rowbase = ((size_t)(b * TT + t)) * DIM + h * DH;
    const float q0 = q[rowbase + lane], q1 = q[rowbase + 64 + lane];

    float s[11];
#pragma unroll
    for (int o = 0; o < 11; ++o) {
        int pos = t + o - 5;
        bool valid = (pos >= 0 && pos < TT);
        float p = 0.0f;
        if (valid) {
            size_t kb = ((size_t)(b * TT + pos)) * DIM + h * DH;
            p = q0 * k[kb + lane] + q1 * k[kb + 64 + lane];
        }
        for (int off = 32; off; off >>= 1) p += __shfl_xor(p, off, 64);
        s[o] = valid ? p / sqrtf(128.0f) : -1e9f;
    }
    float m = s[0];
#pragma unroll
    for (int o = 1; o < 11; ++o) m = fmaxf(m, s[o]);
    float e[11], sum = 0.0f;
#pragma unroll
    for (int o = 0; o < 11; ++o) { e[o] = expf(s[o] - m); sum += e[o]; }

    float o0 = 0.0f, o1 = 0.0f;
#pragma unroll
    for (int o = 0; o < 11; ++o) {
        int pos = t + o - 5;
        if (pos < 0 || pos >= TT) continue;
        float a = e[o] / sum;
        size_t vb = ((size_t)(b * TT + pos)) * DIM + h * DH;
        o0 = fmaf(a, v[vb + lane], o0);
        o1 = fmaf(a, v[vb + 64 + lane], o1);
    }
    out[rowbase + lane]      = o0;
    out[rowbase + 64 + lane] = o1;
}

// ---------------------------------------------------------------------------
// 5x5 gaussian smoothing, SAME/zero-pad, in-place; f64 accumulate
// ---------------------------------------------------------------------------
__global__ __launch_bounds__(256) void k_conv(float* __restrict__ img)
{
    __shared__ float tile[GG];
    __shared__ float w[25];
    float* base = img + (size_t)blockIdx.x * GG;
    for (int i = threadIdx.x; i < GG; i += 256) tile[i] = base[i];
    if (threadIdx.x < 25) {
        int ki = threadIdx.x / 5, kj = threadIdx.x % 5;
        double gi = exp(-0.5 * (double)((ki - 2) * (ki - 2)));
        double gj = exp(-0.5 * (double)((kj - 2) * (kj - 2)));
        double Z  = 1.0 + 2.0 * exp(-0.5) + 2.0 * exp(-2.0);
        w[threadIdx.x] = (float)(gi * gj / (Z * Z));
    }
    __syncthreads();
    for (int p = threadIdx.x; p < GG; p += 256) {
        int y = p / 45, xx = p % 45;
        double acc = 0.0;
#pragma unroll
        for (int i = 0; i < 5; ++i) {
            int yy = y + i - 2;
            if (yy < 0 || yy >= 45) continue;
#pragma unroll
            for (int j = 0; j < 5; ++j) {
                int xj = xx + j - 2;
                if (xj < 0 || xj >= 45) continue;
                acc = fma((double)w[i * 5 + j], (double)tile[yy * 45 + xj], acc);
            }
        }
        base[p] = (float)acc;
    }
}

// ---------------------------------------------------------------------------
// top-40 one-hot per row of 2048; iterative argmax, tie -> lower index
// ---------------------------------------------------------------------------
__global__ __launch_bounds__(256) void k_topk(
    const float* __restrict__ scores, float* __restrict__ sdr)
{
    __shared__ float vals[SS];
    __shared__ float rv[4];
    __shared__ int   ri[4];
    const int row = blockIdx.x;
    const float* srow = scores + (size_t)row * SS;
    float* drow = sdr + (size_t)row * SS;
    for (int i = threadIdx.x; i < SS; i += 256) { vals[i] = srow[i]; drow[i] = 0.0f; }
    __syncthreads();
    const int lane = threadIdx.x & 63, wid = threadIdx.x >> 6;
    for (int it = 0; it < KTOP; ++it) {
        float bv = -INFINITY; int bi = 0x7fffffff;
        for (int i = threadIdx.x; i < SS; i += 256) {
            float vv = vals[i];
            if (vv > bv) { bv = vv; bi = i; }
        }
        for (int off = 32; off; off >>= 1) {
            float ov = __shfl_xor(bv, off, 64);
            int   oi = __shfl_xor(bi, off, 64);
            if (ov > bv || (ov == bv && oi < bi)) { bv = ov; bi = oi; }
        }
        if (lane == 0) { rv[wid] = bv; ri[wid] = bi; }
        __syncthreads();
        if (threadIdx.x == 0) {
            float fv = rv[0]; int fi = ri[0];
            for (int wdx = 1; wdx < 4; ++wdx)
                if (rv[wdx] > fv || (rv[wdx] == fv && ri[wdx] < fi)) { fv = rv[wdx]; fi = ri[wdx]; }
            vals[fi] = -INFINITY;
            drow[fi] = 1.0f;
        }
        __syncthreads();
    }
}

// ---------------------------------------------------------------------------
// All intermediates live inside d_out (134 MB for f32 outputs). Zero d_ws use.
//
// slot0 = d_out[0 .. 16.77M)       (final: sdr)
// slot1 = d_out[16.77M .. 33.55M)  (final: scores)
//
// timeline:                           slot0                  slot1
//  1 embed_ln  -> x, xn               x@0  xn@3SZ
//  2 q,k,v GEMM (reads xn)                                   q@0 k@SZ v@2SZ
//  3 gate GEMM (reads xn)                                    gate@3SZ
//  4 attn(q,k,v) -> attn              attn@SZ
//  5 gateres(attn;x,gate) -> ctx      ctx@2SZ
//  6 gelu(ctx) -> h1 (8.39M)                                 h1@0   (q,k dead)
//  7 w2(h1) -> grid (16.59M)          grid@0 (x,attn,ctx,xn dead)
//  8 conv(grid) in place              grid
//  9 wf(grid) -> scores                                      scores (h1 dead)
// 10 topk(scores) -> sdr              sdr
// ---------------------------------------------------------------------------
extern "C" void kernel_launch(void* const* d_in, const int* in_sizes, int n_in,
                              void* d_out, int out_size, void* d_ws, size_t ws_size,
                              hipStream_t stream)
{
    (void)d_ws; (void)ws_size; (void)in_sizes; (void)n_in; (void)out_size;

    const int*   tokens = (const int*)d_in[0];
    const float* table  = (const float*)d_in[1];
    const float* ln_g   = (const float*)d_in[2];
    const float* ln_b   = (const float*)d_in[3];
    const float* wq = (const float*)d_in[4];  const float* bq = (const float*)d_in[5];
    const float* wk = (const float*)d_in[6];  const float* bk = (const float*)d_in[7];
    const float* wv = (const float*)d_in[8];  const float* bv = (const float*)d_in[9];
    const float* wo = (const float*)d_in[10]; const float* bo = (const float*)d_in[11];
    const float* wg = (const float*)d_in[12]; const float* bg = (const float*)d_in[13];
    const float* w1 = (const float*)d_in[14]; const float* b1 = (const float*)d_in[15];
    const float* w2 = (const float*)d_in[16]; const float* b2 = (const float*)d_in[17];
    const float* wf = (const float*)d_in[18];

    const size_t SZ = (size_t)NROW * DIM;          // 4,194,304 floats
    float* slot0 = (float*)d_out;                  // 16,777,216 floats
    float* slot1 = slot0 + (size_t)NROW * SS;      // 16,777,216 floats

    float* x    = slot0;
    float* attn = slot0 + SZ;
    float* ctx  = slot0 + 2 * SZ;
    float* xn   = slot0 + 3 * SZ;
    float* q    = slot1;
    float* kbuf = slot1 + SZ;
    float* vbuf = slot1 + 2 * SZ;
    float* gate = slot1 + 3 * SZ;                  // 4*SZ == slot size exactly
    float* h1   = slot1;                           // 8192x1024, over dead q,k
    float* grid = slot0;                           // 8192x2025, over dead slot0
    float* scores = slot1;                         // final output 1
    float* sdr    = slot0;                         // final output 0

    dim3 blk(256);
    dim3 g512(8, 128), g1024(16, 128), g2025(32, 128), g2048(32, 128);

    k_embed_ln<<<NROW, blk, 0, stream>>>(tokens, table, ln_g, ln_b, x, xn);
    k_gemm<EPI_BIAS,    float> <<<g512,  blk, 0, stream>>>(xn, wq, bq, q,    NROW, DIM, DIM, nullptr, nullptr);
    k_gemm<EPI_BIAS,    float> <<<g512,  blk, 0, stream>>>(xn, wk, bk, kbuf, NROW, DIM, DIM, nullptr, nullptr);
    k_gemm<EPI_BIAS,    float> <<<g512,  blk, 0, stream>>>(xn, wv, bv, vbuf, NROW, DIM, DIM, nullptr, nullptr);
    k_gemm<EPI_SIGMOID, float> <<<g512,  blk, 0, stream>>>(xn, wg, bg, gate, NROW, DIM, DIM, nullptr, nullptr);
    k_attn              <<<NROW, blk, 0, stream>>>(q, kbuf, vbuf, attn);
    k_gemm<EPI_GATERES, float> <<<g512,  blk, 0, stream>>>(attn, wo, bo, ctx, NROW, DIM, DIM, x, gate);
    k_gemm<EPI_GELU,    float> <<<g1024, blk, 0, stream>>>(ctx, w1, b1, h1,   NROW, 2 * DIM, DIM, nullptr, nullptr);
    k_gemm<EPI_BIAS,    double><<<g2025, blk, 0, stream>>>(h1, w2, b2, grid,  NROW, GG, 2 * DIM, nullptr, nullptr);
    k_conv              <<<NROW, blk, 0, stream>>>(grid);
    k_gemm<EPI_NONE,    double><<<g2048, blk, 0, stream>>>(grid, wf, nullptr, scores, NROW, SS, GG, nullptr, nullptr);
    k_topk              <<<NROW, blk, 0, stream>>>(scores, sdr);
}

// Round 3
// 2594.592 us; speedup vs baseline: 1.3714x; 1.3714x over previous
//
#include <hip/hip_runtime.h>
#include <math.h>

// Problem constants
#define NROW 8192   // B*T
#define DIM  512
#define TT   2048
#define HH   4
#define DH   128
#define GG   2025   // GH*GW
#define SS   2048
#define KTOP 40

// ---------------------------------------------------------------------------
// embed gather + layernorm:  x = table[tok], xn = LN(x)*g + b
// ---------------------------------------------------------------------------
__global__ __launch_bounds__(256) void k_embed_ln(
    const int* __restrict__ tokens, const float* __restrict__ table,
    const float* __restrict__ g, const float* __restrict__ b,
    float* __restrict__ x, float* __restrict__ xn)
{
    __shared__ float red[4];
    const int row = blockIdx.x;
    const int tid = threadIdx.x;
    const float* src = table + (size_t)tokens[row] * DIM;
    float v0 = src[tid], v1 = src[tid + 256];

    float s = v0 + v1;
    for (int off = 32; off; off >>= 1) s += __shfl_xor(s, off, 64);
    if ((tid & 63) == 0) red[tid >> 6] = s;
    __syncthreads();
    float mean = (red[0] + red[1] + red[2] + red[3]) * (1.0f / 512.0f);
    __syncthreads();

    float d0 = v0 - mean, d1 = v1 - mean;
    float ss = d0 * d0 + d1 * d1;
    for (int off = 32; off; off >>= 1) ss += __shfl_xor(ss, off, 64);
    if ((tid & 63) == 0) red[tid >> 6] = ss;
    __syncthreads();
    float var = (red[0] + red[1] + red[2] + red[3]) * (1.0f / 512.0f);
    float rs = 1.0f / sqrtf(var + 1e-5f);

    size_t base = (size_t)row * DIM;
    x[base + tid]        = v0;
    x[base + tid + 256]  = v1;
    xn[base + tid]       = d0 * rs * g[tid] + b[tid];
    xn[base + tid + 256] = d1 * rs * g[tid + 256] + b[tid + 256];
}

// ---------------------------------------------------------------------------
// f32 GEMM  C = epi(A @ B + bias). A: MxK, B: KxN row-major.
// 64x64 tile, BK=16, 256 thr, 4x4/thread.
// ---------------------------------------------------------------------------
enum { EPI_BIAS = 0, EPI_SIGMOID = 1, EPI_GATERES = 2, EPI_GELU = 3, EPI_NONE = 4 };

template<int EPI>
__global__ __launch_bounds__(256) void k_gemm(
    const float* __restrict__ A, const float* __restrict__ B,
    const float* __restrict__ bias, float* __restrict__ C,
    int M, int N, int K,
    const float* __restrict__ resid, const float* __restrict__ gate)
{
    __shared__ float As[16][68];
    __shared__ float Bs[16][64];
    const int tid = threadIdx.x;
    const int tx = tid & 15, ty = tid >> 4;
    const int bm = blockIdx.y * 64, bn = blockIdx.x * 64;
    float acc[4][4] = {};

    const int la_k = tid & 15, la_m = tid >> 4;
    const int lb_n = tid & 63, lb_k = tid >> 6;

    for (int k0 = 0; k0 < K; k0 += 16) {
#pragma unroll
        for (int i = 0; i < 4; ++i) {
            int m = bm + la_m + 16 * i, k = k0 + la_k;
            As[la_k][la_m + 16 * i] = (m < M && k < K) ? A[(size_t)m * K + k] : 0.0f;
        }
#pragma unroll
        for (int i = 0; i < 4; ++i) {
            int k = k0 + lb_k + 4 * i;
            Bs[lb_k + 4 * i][lb_n] = (k < K && bn + lb_n < N) ? B[(size_t)k * N + bn + lb_n] : 0.0f;
        }
        __syncthreads();
#pragma unroll
        for (int kk = 0; kk < 16; ++kk) {
            float4 a4 = *(const float4*)&As[kk][ty * 4];
            float4 b4 = *(const float4*)&Bs[kk][tx * 4];
            float av[4] = {a4.x, a4.y, a4.z, a4.w};
            float bv[4] = {b4.x, b4.y, b4.z, b4.w};
#pragma unroll
            for (int i = 0; i < 4; ++i)
#pragma unroll
                for (int j = 0; j < 4; ++j)
                    acc[i][j] = fmaf(av[i], bv[j], acc[i][j]);
        }
        __syncthreads();
    }

#pragma unroll
    for (int i = 0; i < 4; ++i) {
        int m = bm + ty * 4 + i;
        if (m >= M) continue;
#pragma unroll
        for (int j = 0; j < 4; ++j) {
            int n = bn + tx * 4 + j;
            if (n >= N) continue;
            size_t idx = (size_t)m * N + n;
            float t = acc[i][j];
            if (EPI != EPI_NONE) t += bias[n];
            float r;
            if (EPI == EPI_SIGMOID)      r = 1.0f / (1.0f + expf(-t));
            else if (EPI == EPI_GATERES) r = resid[idx] + gate[idx] * t;
            else if (EPI == EPI_GELU)    r = 0.5f * t * (1.0f + erff(t * 0.70710678118654752440f));
            else                         r = t;
            C[idx] = r;
        }
    }
}

// ---------------------------------------------------------------------------
// f64-accumulate GEMM with f64 LDS tiles (convert once per element, not per
// FMA).  A: f32 MxK.  B: TB KxN.  C: TC MxN.  Optional f64 bias (EPI_BIAS).
// As2[m][k] layout -> inner-loop A reads are wave-broadcast (conflict-free);
// Bs[k][n] reads are 2x ds_read_b128 at the HW-minimum 2-way aliasing.
// ---------------------------------------------------------------------------
template<int EPI, typename TB, typename TC>
__global__ __launch_bounds__(256) void k_gemm64(
    const float* __restrict__ A, const TB* __restrict__ B,
    const double* __restrict__ bias, TC* __restrict__ C,
    int M, int N, int K)
{
    __shared__ double As2[64][16];
    __shared__ double Bs[16][64];
    const int tid = threadIdx.x;
    const int tx = tid & 15, ty = tid >> 4;
    const int bm = blockIdx.y * 64, bn = blockIdx.x * 64;
    double acc[4][4] = {};

    const int la_k = tid & 15, la_m = tid >> 4;
    const int lb_n = tid & 63, lb_k = tid >> 6;

    for (int k0 = 0; k0 < K; k0 += 16) {
#pragma unroll
        for (int i = 0; i < 4; ++i) {
            int m = bm + la_m + 16 * i, k = k0 + la_k;
            As2[la_m + 16 * i][la_k] = (m < M && k < K) ? (double)A[(size_t)m * K + k] : 0.0;
        }
#pragma unroll
        for (int i = 0; i < 4; ++i) {
            int k = k0 + lb_k + 4 * i;
            Bs[lb_k + 4 * i][lb_n] = (k < K && bn + lb_n < N) ? (double)B[(size_t)k * N + bn + lb_n] : 0.0;
        }
        __syncthreads();
#pragma unroll
        for (int kk = 0; kk < 16; ++kk) {
            double av[4], bv[4];
#pragma unroll
            for (int i = 0; i < 4; ++i) av[i] = As2[ty * 4 + i][kk];
#pragma unroll
            for (int j = 0; j < 4; ++j) bv[j] = Bs[kk][tx * 4 + j];
#pragma unroll
            for (int i = 0; i < 4; ++i)
#pragma unroll
                for (int j = 0; j < 4; ++j)
                    acc[i][j] = fma(av[i], bv[j], acc[i][j]);
        }
        __syncthreads();
    }

#pragma unroll
    for (int i = 0; i < 4; ++i) {
        int m = bm + ty * 4 + i;
        if (m >= M) continue;
#pragma unroll
        for (int j = 0; j < 4; ++j) {
            int n = bn + tx * 4 + j;
            if (n >= N) continue;
            double t = acc[i][j];
            if (EPI == EPI_BIAS) t += bias[n];
            C[(size_t)m * N + n] = (TC)t;
        }
    }
}

// ---------------------------------------------------------------------------
// banded attention, window half-width 5 (W=11). One wave per (b,t,h).
// ---------------------------------------------------------------------------
__global__ __launch_bounds__(256) void k_attn(
    const float* __restrict__ q, const float* __restrict__ k,
    const float* __restrict__ v, float* __restrict__ out)
{
    const int w    = (blockIdx.x << 2) + (threadIdx.x >> 6);
    const int lane = threadIdx.x & 63;
    const int h = w & 3;
    const int t = (w >> 2) & 2047;
    const int b = w >> 13;
    const size_t rowbase = ((size_t)(b * TT + t)) * DIM + h * DH;
    const float q0 = q[rowbase + lane], q1 = q[rowbase + 64 + lane];

    float s[11];
#pragma unroll
    for (int o = 0; o < 11; ++o) {
        int pos = t + o - 5;
        bool valid = (pos >= 0 && pos < TT);
        float p = 0.0f;
        if (valid) {
            size_t kb = ((size_t)(b * TT + pos)) * DIM + h * DH;
            p = q0 * k[kb + lane] + q1 * k[kb + 64 + lane];
        }
        for (int off = 32; off; off >>= 1) p += __shfl_xor(p, off, 64);
        s[o] = valid ? p / sqrtf(128.0f) : -1e9f;
    }
    float m = s[0];
#pragma unroll
    for (int o = 1; o < 11; ++o) m = fmaxf(m, s[o]);
    float e[11], sum = 0.0f;
#pragma unroll
    for (int o = 0; o < 11; ++o) { e[o] = expf(s[o] - m); sum += e[o]; }

    float o0 = 0.0f, o1 = 0.0f;
#pragma unroll
    for (int o = 0; o < 11; ++o) {
        int pos = t + o - 5;
        if (pos < 0 || pos >= TT) continue;
        float a = e[o] / sum;
        size_t vb = ((size_t)(b * TT + pos)) * DIM + h * DH;
        o0 = fmaf(a, v[vb + lane], o0);
        o1 = fmaf(a, v[vb + 64 + lane], o1);
    }
    out[rowbase + lane]      = o0;
    out[rowbase + 64 + lane] = o1;
}

// ---------------------------------------------------------------------------
// wf2[q,s] = sum_p L[q,p] * wf[p,s]   (conv applied to wf's grid index;
// L symmetric Gaussian w/ zero-pad SAME). One block per q, f64 accumulate.
// ---------------------------------------------------------------------------
__global__ __launch_bounds__(256) void k_conv_wf(
    const float* __restrict__ wf, double* __restrict__ wf2)
{
    __shared__ float w[25];
    const int qq = blockIdx.x;
    const int y = qq / 45, x = qq % 45;
    if (threadIdx.x < 25) {
        int ki = threadIdx.x / 5, kj = threadIdx.x % 5;
        double gi = exp(-0.5 * (double)((ki - 2) * (ki - 2)));
        double gj = exp(-0.5 * (double)((kj - 2) * (kj - 2)));
        double Z  = 1.0 + 2.0 * exp(-0.5) + 2.0 * exp(-2.0);
        w[threadIdx.x] = (float)(gi * gj / (Z * Z));
    }
    __syncthreads();
    for (int s = threadIdx.x; s < SS; s += 256) {
        double acc = 0.0;
#pragma unroll
        for (int dy = -2; dy <= 2; ++dy) {
            int yy = y + dy;
            if (yy < 0 || yy >= 45) continue;
#pragma unroll
            for (int dx = -2; dx <= 2; ++dx) {
                int xx2 = x + dx;
                if (xx2 < 0 || xx2 >= 45) continue;
                acc = fma((double)w[(dy + 2) * 5 + (dx + 2)],
                          (double)wf[(size_t)(yy * 45 + xx2) * SS + s], acc);
            }
        }
        wf2[(size_t)qq * SS + s] = acc;
    }
}

// c[s] = sum_q b2[q] * wf2[q,s]
__global__ __launch_bounds__(256) void k_bias_c(
    const float* __restrict__ b2, const double* __restrict__ wf2,
    double* __restrict__ c)
{
    const int s = blockIdx.x * 256 + threadIdx.x;
    double acc = 0.0;
    for (int qq = 0; qq < GG; ++qq)
        acc = fma((double)b2[qq], wf2[(size_t)qq * SS + s], acc);
    c[s] = acc;
}

// ---------------------------------------------------------------------------
// top-40 one-hot per row of 2048; iterative argmax, tie -> lower index
// ---------------------------------------------------------------------------
__global__ __launch_bounds__(256) void k_topk(
    const float* __restrict__ scores, float* __restrict__ sdr)
{
    __shared__ float vals[SS];
    __shared__ float rv[4];
    __shared__ int   ri[4];
    const int row = blockIdx.x;
    const float* srow = scores + (size_t)row * SS;
    float* drow = sdr + (size_t)row * SS;
    for (int i = threadIdx.x; i < SS; i += 256) { vals[i] = srow[i]; drow[i] = 0.0f; }
    __syncthreads();
    const int lane = threadIdx.x & 63, wid = threadIdx.x >> 6;
    for (int it = 0; it < KTOP; ++it) {
        float bv = -INFINITY; int bi = 0x7fffffff;
        for (int i = threadIdx.x; i < SS; i += 256) {
            float vv = vals[i];
            if (vv > bv) { bv = vv; bi = i; }
        }
        for (int off = 32; off; off >>= 1) {
            float ov = __shfl_xor(bv, off, 64);
            int   oi = __shfl_xor(bi, off, 64);
            if (ov > bv || (ov == bv && oi < bi)) { bv = ov; bi = oi; }
        }
        if (lane == 0) { rv[wid] = bv; ri[wid] = bi; }
        __syncthreads();
        if (threadIdx.x == 0) {
            float fv = rv[0]; int fi = ri[0];
            for (int wdx = 1; wdx < 4; ++wdx)
                if (rv[wdx] > fv || (rv[wdx] == fv && ri[wdx] < fi)) { fv = rv[wdx]; fi = ri[wdx]; }
            vals[fi] = -INFINITY;
            drow[fi] = 1.0f;
        }
        __syncthreads();
    }
}

// ---------------------------------------------------------------------------
// All intermediates inside d_out. slot0/slot1 = 16,777,216 floats each.
//
//  1 embed_ln          -> x@s0+0, xn@s0+3SZ
//  2 q,k,v GEMM        -> q@s1+0, k@s1+SZ, v@s1+2SZ
//  3 gate GEMM         -> gate@s1+3SZ
//  4 attn              -> attn@s0+SZ                (q,k dead after)
//  5 gateres           -> ctx@s0+2SZ                (x, attn, gate dead after)
//  6 gelu GEMM         -> h1@s0+0 (2SZ)             (reads ctx; x,attn dead)
//  7 conv_wf           -> wf2 (f64)@s1+0 (8.29M fl) (q,k dead; v untouched)
//  8 bias_c            -> c (f64)@s0+4SZ-4096       (xn dead)
//  9 W = w2@wf2 (f64)  -> W (f64)@s0+2SZ (SZ fl)    (ctx dead after 6)
// 10 scores = h1@W + c -> scores@s1                 (wf2, v dead)
// 11 topk              -> sdr@s0                    (h1, W, c dead)
// ---------------------------------------------------------------------------
extern "C" void kernel_launch(void* const* d_in, const int* in_sizes, int n_in,
                              void* d_out, int out_size, void* d_ws, size_t ws_size,
                              hipStream_t stream)
{
    (void)d_ws; (void)ws_size; (void)in_sizes; (void)n_in; (void)out_size;

    const int*   tokens = (const int*)d_in[0];
    const float* table  = (const float*)d_in[1];
    const float* ln_g   = (const float*)d_in[2];
    const float* ln_b   = (const float*)d_in[3];
    const float* wq = (const float*)d_in[4];  const float* bq = (const float*)d_in[5];
    const float* wk = (const float*)d_in[6];  const float* bk = (const float*)d_in[7];
    const float* wv = (const float*)d_in[8];  const float* bv = (const float*)d_in[9];
    const float* wo = (const float*)d_in[10]; const float* bo = (const float*)d_in[11];
    const float* wg = (const float*)d_in[12]; const float* bg = (const float*)d_in[13];
    const float* w1 = (const float*)d_in[14]; const float* b1 = (const float*)d_in[15];
    const float* w2 = (const float*)d_in[16]; const float* b2 = (const float*)d_in[17];
    const float* wf = (const float*)d_in[18];

    const size_t SZ = (size_t)NROW * DIM;          // 4,194,304 floats
    float* slot0 = (float*)d_out;
    float* slot1 = slot0 + (size_t)NROW * SS;

    float* x    = slot0;
    float* attn = slot0 + SZ;
    float* ctx  = slot0 + 2 * SZ;
    float* xn   = slot0 + 3 * SZ;
    float* q    = slot1;
    float* kbuf = slot1 + SZ;
    float* vbuf = slot1 + 2 * SZ;
    float* gate = slot1 + 3 * SZ;
    float*  h1   = slot0;                                  // 8192x1024 f32
    double* wf2  = (double*)slot1;                         // 2025x2048 f64
    double* Wd   = (double*)(slot0 + 2 * SZ);              // 1024x2048 f64 (= SZ floats)
    double* cvec = (double*)(slot0 + 4 * SZ - 4096);       // 2048 f64
    float* scores = slot1;
    float* sdr    = slot0;

    dim3 blk(256);
    dim3 g512(8, 128), g1024(16, 128), gW(32, 16), g2048(32, 128);

    k_embed_ln<<<NROW, blk, 0, stream>>>(tokens, table, ln_g, ln_b, x, xn);
    k_gemm<EPI_BIAS>   <<<g512,  blk, 0, stream>>>(xn, wq, bq, q,    NROW, DIM, DIM, nullptr, nullptr);
    k_gemm<EPI_BIAS>   <<<g512,  blk, 0, stream>>>(xn, wk, bk, kbuf, NROW, DIM, DIM, nullptr, nullptr);
    k_gemm<EPI_BIAS>   <<<g512,  blk, 0, stream>>>(xn, wv, bv, vbuf, NROW, DIM, DIM, nullptr, nullptr);
    k_gemm<EPI_SIGMOID><<<g512,  blk, 0, stream>>>(xn, wg, bg, gate, NROW, DIM, DIM, nullptr, nullptr);
    k_attn             <<<NROW,  blk, 0, stream>>>(q, kbuf, vbuf, attn);
    k_gemm<EPI_GATERES><<<g512,  blk, 0, stream>>>(attn, wo, bo, ctx, NROW, DIM, DIM, x, gate);
    k_gemm<EPI_GELU>   <<<g1024, blk, 0, stream>>>(ctx, w1, b1, h1,   NROW, 2 * DIM, DIM, nullptr, nullptr);
    k_conv_wf          <<<GG,    blk, 0, stream>>>(wf, wf2);
    k_bias_c           <<<SS/256, blk, 0, stream>>>(b2, wf2, cvec);
    k_gemm64<EPI_NONE, double, double><<<gW,    blk, 0, stream>>>(w2, wf2, nullptr, Wd,     1024, SS, GG);
    k_gemm64<EPI_BIAS, double, float> <<<g2048, blk, 0, stream>>>(h1, Wd,  cvec,    scores, NROW, SS, 2 * DIM);
    k_topk             <<<NROW,  blk, 0, stream>>>(scores, sdr);
}

// Round 4
// 2220.048 us; speedup vs baseline: 1.6028x; 1.1687x over previous
//
#include <hip/hip_runtime.h>
#include <math.h>

// Problem constants
#define NROW 8192   // B*T
#define DIM  512
#define TT   2048
#define HH   4
#define DH   128
#define GG   2025   // GH*GW
#define SS   2048
#define KTOP 40

// ---------------------------------------------------------------------------
// embed gather + layernorm:  x = table[tok], xn = LN(x)*g + b
// ---------------------------------------------------------------------------
__global__ __launch_bounds__(256) void k_embed_ln(
    const int* __restrict__ tokens, const float* __restrict__ table,
    const float* __restrict__ g, const float* __restrict__ b,
    float* __restrict__ x, float* __restrict__ xn)
{
    __shared__ float red[4];
    const int row = blockIdx.x;
    const int tid = threadIdx.x;
    const float* src = table + (size_t)tokens[row] * DIM;
    float v0 = src[tid], v1 = src[tid + 256];

    float s = v0 + v1;
    for (int off = 32; off; off >>= 1) s += __shfl_xor(s, off, 64);
    if ((tid & 63) == 0) red[tid >> 6] = s;
    __syncthreads();
    float mean = (red[0] + red[1] + red[2] + red[3]) * (1.0f / 512.0f);
    __syncthreads();

    float d0 = v0 - mean, d1 = v1 - mean;
    float ss = d0 * d0 + d1 * d1;
    for (int off = 32; off; off >>= 1) ss += __shfl_xor(ss, off, 64);
    if ((tid & 63) == 0) red[tid >> 6] = ss;
    __syncthreads();
    float var = (red[0] + red[1] + red[2] + red[3]) * (1.0f / 512.0f);
    float rs = 1.0f / sqrtf(var + 1e-5f);

    size_t base = (size_t)row * DIM;
    x[base + tid]        = v0;
    x[base + tid + 256]  = v1;
    xn[base + tid]       = d0 * rs * g[tid] + b[tid];
    xn[base + tid + 256] = d1 * rs * g[tid + 256] + b[tid + 256];
}

// ---------------------------------------------------------------------------
// f32 GEMM  C = epi(A @ B + bias). A: MxK, B: KxN row-major.
// 128x128 tile, BK=16, 256 thr, 8x8/thread. REQUIRES M%128==0, N%128==0,
// K%16==0 (all call sites satisfy). K-accumulation order identical to the
// round-2/3 kernel (sequential k) -> bitwise-identical results.
// LDS pad 132 floats/row: A-frag reads broadcast+conflict-free, B-frag 2-way.
// ---------------------------------------------------------------------------
enum { EPI_BIAS = 0, EPI_SIGMOID = 1, EPI_GATERES = 2, EPI_GELU = 3, EPI_NONE = 4 };

template<int EPI>
__global__ __launch_bounds__(256) void k_gemm_f32(
    const float* __restrict__ A, const float* __restrict__ B,
    const float* __restrict__ bias, float* __restrict__ C,
    int M, int N, int K,
    const float* __restrict__ resid, const float* __restrict__ gate)
{
    __shared__ float As[16][132];   // [k][m]
    __shared__ float Bs[16][132];   // [k][n]
    const int tid = threadIdx.x;
    const int tx = tid & 15, ty = tid >> 4;
    const int bm = blockIdx.y * 128, bn = blockIdx.x * 128;
    float acc[8][8] = {};

    const int a_m = tid >> 2;          // 0..63 (row; also row+64)
    const int a_c = (tid & 3) * 4;     // k-offset {0,4,8,12}
    const int b_r = tid >> 5;          // 0..7  (k-row; also +8)
    const int b_n = (tid & 31) * 4;    // col chunk

    const float* Arow0 = A + (size_t)(bm + a_m) * K + a_c;
    const float* Arow1 = A + (size_t)(bm + a_m + 64) * K + a_c;
    const float* Brow0 = B + (size_t)b_r * N + bn + b_n;
    const float* Brow1 = B + (size_t)(b_r + 8) * N + bn + b_n;

    for (int k0 = 0; k0 < K; k0 += 16) {
        float4 av0 = *(const float4*)(Arow0 + k0);
        float4 av1 = *(const float4*)(Arow1 + k0);
        float4 bv0 = *(const float4*)(Brow0 + (size_t)k0 * N);
        float4 bv1 = *(const float4*)(Brow1 + (size_t)k0 * N);
        __syncthreads();                       // prev-tile reads done
        As[a_c + 0][a_m] = av0.x; As[a_c + 1][a_m] = av0.y;
        As[a_c + 2][a_m] = av0.z; As[a_c + 3][a_m] = av0.w;
        As[a_c + 0][a_m + 64] = av1.x; As[a_c + 1][a_m + 64] = av1.y;
        As[a_c + 2][a_m + 64] = av1.z; As[a_c + 3][a_m + 64] = av1.w;
        *(float4*)&Bs[b_r][b_n]     = bv0;
        *(float4*)&Bs[b_r + 8][b_n] = bv1;
        __syncthreads();                       // tile ready
#pragma unroll
        for (int kk = 0; kk < 16; ++kk) {
            float4 a0 = *(const float4*)&As[kk][ty * 4];
            float4 a1 = *(const float4*)&As[kk][64 + ty * 4];
            float4 b0 = *(const float4*)&Bs[kk][tx * 4];
            float4 b1 = *(const float4*)&Bs[kk][64 + tx * 4];
            float av[8] = {a0.x, a0.y, a0.z, a0.w, a1.x, a1.y, a1.z, a1.w};
            float bv[8] = {b0.x, b0.y, b0.z, b0.w, b1.x, b1.y, b1.z, b1.w};
#pragma unroll
            for (int i = 0; i < 8; ++i)
#pragma unroll
                for (int j = 0; j < 8; ++j)
                    acc[i][j] = fmaf(av[i], bv[j], acc[i][j]);
        }
    }

#pragma unroll
    for (int i = 0; i < 8; ++i) {
        int m = bm + 4 * ty + (i & 3) + (i >> 2) * 64;
#pragma unroll
        for (int half = 0; half < 2; ++half) {
            int n0 = bn + 4 * tx + half * 64;
            size_t idx = (size_t)m * N + n0;
            float4 o;
            float* oo = (float*)&o;
#pragma unroll
            for (int j = 0; j < 4; ++j) {
                float t = acc[i][half * 4 + j];
                if (EPI != EPI_NONE) t += bias[n0 + j];
                float r;
                if (EPI == EPI_SIGMOID)      r = 1.0f / (1.0f + expf(-t));
                else if (EPI == EPI_GATERES) r = resid[idx + j] + gate[idx + j] * t;
                else if (EPI == EPI_GELU)    r = 0.5f * t * (1.0f + erff(t * 0.70710678118654752440f));
                else                         r = t;
                oo[j] = r;
            }
            *(float4*)&C[idx] = o;
        }
    }
}

// ---------------------------------------------------------------------------
// f64-accumulate GEMM, conflict-free LDS:
//   As2[64][17]: A-frag reads -> 4 distinct banks, broadcast x16
//   Bs[16][65] + per-thread cols tx+16j -> 16 distinct bank-pairs, broadcast x4
// A: f32 MxK.  B: f64 KxN.  C: TC MxN.  Optional f64 bias (EPI_BIAS).
// Same K-accumulation order as round 3.
// ---------------------------------------------------------------------------
template<int EPI, typename TC>
__global__ __launch_bounds__(256) void k_gemm64(
    const float* __restrict__ A, const double* __restrict__ B,
    const double* __restrict__ bias, TC* __restrict__ C,
    int M, int N, int K)
{
    __shared__ double As2[64][17];
    __shared__ double Bs[16][65];
    const int tid = threadIdx.x;
    const int tx = tid & 15, ty = tid >> 4;
    const int bm = blockIdx.y * 64, bn = blockIdx.x * 64;
    double acc[4][4] = {};

    const int la_k = tid & 15, la_m = tid >> 4;
    const int lb_n = tid & 63, lb_k = tid >> 6;

    for (int k0 = 0; k0 < K; k0 += 16) {
        double a_r[4], b_r[4];
#pragma unroll
        for (int i = 0; i < 4; ++i) {
            int m = bm + la_m + 16 * i, k = k0 + la_k;
            a_r[i] = (m < M && k < K) ? (double)A[(size_t)m * K + k] : 0.0;
        }
#pragma unroll
        for (int i = 0; i < 4; ++i) {
            int k = k0 + lb_k + 4 * i;
            b_r[i] = (k < K && bn + lb_n < N) ? B[(size_t)k * N + bn + lb_n] : 0.0;
        }
        __syncthreads();
#pragma unroll
        for (int i = 0; i < 4; ++i) As2[la_m + 16 * i][la_k] = a_r[i];
#pragma unroll
        for (int i = 0; i < 4; ++i) Bs[lb_k + 4 * i][lb_n] = b_r[i];
        __syncthreads();
#pragma unroll
        for (int kk = 0; kk < 16; ++kk) {
            double av[4], bv[4];
#pragma unroll
            for (int i = 0; i < 4; ++i) av[i] = As2[ty * 4 + i][kk];
#pragma unroll
            for (int j = 0; j < 4; ++j) bv[j] = Bs[kk][tx + 16 * j];
#pragma unroll
            for (int i = 0; i < 4; ++i)
#pragma unroll
                for (int j = 0; j < 4; ++j)
                    acc[i][j] = fma(av[i], bv[j], acc[i][j]);
        }
        __syncthreads();
    }

#pragma unroll
    for (int i = 0; i < 4; ++i) {
        int m = bm + ty * 4 + i;
        if (m >= M) continue;
#pragma unroll
        for (int j = 0; j < 4; ++j) {
            int n = bn + tx + 16 * j;
            if (n >= N) continue;
            double t = acc[i][j];
            if (EPI == EPI_BIAS) t += bias[n];
            C[(size_t)m * N + n] = (TC)t;
        }
    }
}

// ---------------------------------------------------------------------------
// banded attention, window half-width 5 (W=11). One wave per (b,t,h).
// ---------------------------------------------------------------------------
__global__ __launch_bounds__(256) void k_attn(
    const float* __restrict__ q, const float* __restrict__ k,
    const float* __restrict__ v, float* __restrict__ out)
{
    const int w    = (blockIdx.x << 2) + (threadIdx.x >> 6);
    const int lane = threadIdx.x & 63;
    const int h = w & 3;
    const int t = (w >> 2) & 2047;
    const int b = w >> 13;
    const size_t rowbase = ((size_t)(b * TT + t)) * DIM + h * DH;
    const float q0 = q[rowbase + lane], q1 = q[rowbase + 64 + lane];

    float s[11];
#pragma unroll
    for (int o = 0; o < 11; ++o) {
        int pos = t + o - 5;
        bool valid = (pos >= 0 && pos < TT);
        float p = 0.0f;
        if (valid) {
            size_t kb = ((size_t)(b * TT + pos)) * DIM + h * DH;
            p = q0 * k[kb + lane] + q1 * k[kb + 64 + lane];
        }
        for (int off = 32; off; off >>= 1) p += __shfl_xor(p, off, 64);
        s[o] = valid ? p / sqrtf(128.0f) : -1e9f;
    }
    float m = s[0];
#pragma unroll
    for (int o = 1; o < 11; ++o) m = fmaxf(m, s[o]);
    float e[11], sum = 0.0f;
#pragma unroll
    for (int o = 0; o < 11; ++o) { e[o] = expf(s[o] - m); sum += e[o]; }

    float o0 = 0.0f, o1 = 0.0f;
#pragma unroll
    for (int o = 0; o < 11; ++o) {
        int pos = t + o - 5;
        if (pos < 0 || pos >= TT) continue;
        float a = e[o] / sum;
        size_t vb = ((size_t)(b * TT + pos)) * DIM + h * DH;
        o0 = fmaf(a, v[vb + lane], o0);
        o1 = fmaf(a, v[vb + 64 + lane], o1);
    }
    out[rowbase + lane]      = o0;
    out[rowbase + 64 + lane] = o1;
}

// ---------------------------------------------------------------------------
// wf2[q,s] = sum_p L[q,p] * wf[p,s]   (conv applied to wf's grid index)
// ---------------------------------------------------------------------------
__global__ __launch_bounds__(256) void k_conv_wf(
    const float* __restrict__ wf, double* __restrict__ wf2)
{
    __shared__ float w[25];
    const int qq = blockIdx.x;
    const int y = qq / 45, x = qq % 45;
    if (threadIdx.x < 25) {
        int ki = threadIdx.x / 5, kj = threadIdx.x % 5;
        double gi = exp(-0.5 * (double)((ki - 2) * (ki - 2)));
        double gj = exp(-0.5 * (double)((kj - 2) * (kj - 2)));
        double Z  = 1.0 + 2.0 * exp(-0.5) + 2.0 * exp(-2.0);
        w[threadIdx.x] = (float)(gi * gj / (Z * Z));
    }
    __syncthreads();
    for (int s = threadIdx.x; s < SS; s += 256) {
        double acc = 0.0;
#pragma unroll
        for (int dy = -2; dy <= 2; ++dy) {
            int yy = y + dy;
            if (yy < 0 || yy >= 45) continue;
#pragma unroll
            for (int dx = -2; dx <= 2; ++dx) {
                int xx2 = x + dx;
                if (xx2 < 0 || xx2 >= 45) continue;
                acc = fma((double)w[(dy + 2) * 5 + (dx + 2)],
                          (double)wf[(size_t)(yy * 45 + xx2) * SS + s], acc);
            }
        }
        wf2[(size_t)qq * SS + s] = acc;
    }
}

// c[s] = sum_q b2[q] * wf2[q,s]  — one wave per s, lane-strided + shfl reduce
__global__ __launch_bounds__(256) void k_bias_c(
    const float* __restrict__ b2, const double* __restrict__ wf2,
    double* __restrict__ c)
{
    const int s = blockIdx.x * 4 + (threadIdx.x >> 6);
    const int lane = threadIdx.x & 63;
    double acc = 0.0;
    for (int qq = lane; qq < GG; qq += 64)
        acc = fma((double)b2[qq], wf2[(size_t)qq * SS + s], acc);
    for (int off = 32; off; off >>= 1) acc += __shfl_xor(acc, off, 64);
    if (lane == 0) c[s] = acc;
}

// ---------------------------------------------------------------------------
// top-40 one-hot per row of 2048; iterative argmax, tie -> lower index
// ---------------------------------------------------------------------------
__global__ __launch_bounds__(256) void k_topk(
    const float* __restrict__ scores, float* __restrict__ sdr)
{
    __shared__ float vals[SS];
    __shared__ float rv[4];
    __shared__ int   ri[4];
    const int row = blockIdx.x;
    const float* srow = scores + (size_t)row * SS;
    float* drow = sdr + (size_t)row * SS;
    for (int i = threadIdx.x; i < SS; i += 256) { vals[i] = srow[i]; drow[i] = 0.0f; }
    __syncthreads();
    const int lane = threadIdx.x & 63, wid = threadIdx.x >> 6;
    for (int it = 0; it < KTOP; ++it) {
        float bv = -INFINITY; int bi = 0x7fffffff;
        for (int i = threadIdx.x; i < SS; i += 256) {
            float vv = vals[i];
            if (vv > bv) { bv = vv; bi = i; }
        }
        for (int off = 32; off; off >>= 1) {
            float ov = __shfl_xor(bv, off, 64);
            int   oi = __shfl_xor(bi, off, 64);
            if (ov > bv || (ov == bv && oi < bi)) { bv = ov; bi = oi; }
        }
        if (lane == 0) { rv[wid] = bv; ri[wid] = bi; }
        __syncthreads();
        if (threadIdx.x == 0) {
            float fv = rv[0]; int fi = ri[0];
            for (int wdx = 1; wdx < 4; ++wdx)
                if (rv[wdx] > fv || (rv[wdx] == fv && ri[wdx] < fi)) { fv = rv[wdx]; fi = ri[wdx]; }
            vals[fi] = -INFINITY;
            drow[fi] = 1.0f;
        }
        __syncthreads();
    }
}

// ---------------------------------------------------------------------------
// All intermediates inside d_out (same placement as round 3, which passed).
// ---------------------------------------------------------------------------
extern "C" void kernel_launch(void* const* d_in, const int* in_sizes, int n_in,
                              void* d_out, int out_size, void* d_ws, size_t ws_size,
                              hipStream_t stream)
{
    (void)d_ws; (void)ws_size; (void)in_sizes; (void)n_in; (void)out_size;

    const int*   tokens = (const int*)d_in[0];
    const float* table  = (const float*)d_in[1];
    const float* ln_g   = (const float*)d_in[2];
    const float* ln_b   = (const float*)d_in[3];
    const float* wq = (const float*)d_in[4];  const float* bq = (const float*)d_in[5];
    const float* wk = (const float*)d_in[6];  const float* bk = (const float*)d_in[7];
    const float* wv = (const float*)d_in[8];  const float* bv = (const float*)d_in[9];
    const float* wo = (const float*)d_in[10]; const float* bo = (const float*)d_in[11];
    const float* wg = (const float*)d_in[12]; const float* bg = (const float*)d_in[13];
    const float* w1 = (const float*)d_in[14]; const float* b1 = (const float*)d_in[15];
    const float* w2 = (const float*)d_in[16]; const float* b2 = (const float*)d_in[17];
    const float* wf = (const float*)d_in[18];

    const size_t SZ = (size_t)NROW * DIM;          // 4,194,304 floats
    float* slot0 = (float*)d_out;
    float* slot1 = slot0 + (size_t)NROW * SS;

    float* x    = slot0;
    float* attn = slot0 + SZ;
    float* ctx  = slot0 + 2 * SZ;
    float* xn   = slot0 + 3 * SZ;
    float* q    = slot1;
    float* kbuf = slot1 + SZ;
    float* vbuf = slot1 + 2 * SZ;
    float* gate = slot1 + 3 * SZ;
    float*  h1   = slot0;                                  // 8192x1024 f32
    double* wf2  = (double*)slot1;                         // 2025x2048 f64
    double* Wd   = (double*)(slot0 + 2 * SZ);              // 1024x2048 f64
    double* cvec = (double*)(slot0 + 4 * SZ - 4096);       // 2048 f64
    float* scores = slot1;
    float* sdr    = slot0;

    dim3 blk(256);
    dim3 g512(4, 64), g1024(8, 64);          // f32 GEMM: 128x128 tiles
    dim3 gW(32, 16), g2048(32, 128);         // f64 GEMM: 64x64 tiles

    k_embed_ln<<<NROW, blk, 0, stream>>>(tokens, table, ln_g, ln_b, x, xn);
    k_gemm_f32<EPI_BIAS>   <<<g512,  blk, 0, stream>>>(xn, wq, bq, q,    NROW, DIM, DIM, nullptr, nullptr);
    k_gemm_f32<EPI_BIAS>   <<<g512,  blk, 0, stream>>>(xn, wk, bk, kbuf, NROW, DIM, DIM, nullptr, nullptr);
    k_gemm_f32<EPI_BIAS>   <<<g512,  blk, 0, stream>>>(xn, wv, bv, vbuf, NROW, DIM, DIM, nullptr, nullptr);
    k_gemm_f32<EPI_SIGMOID><<<g512,  blk, 0, stream>>>(xn, wg, bg, gate, NROW, DIM, DIM, nullptr, nullptr);
    k_attn                 <<<NROW,  blk, 0, stream>>>(q, kbuf, vbuf, attn);
    k_gemm_f32<EPI_GATERES><<<g512,  blk, 0, stream>>>(attn, wo, bo, ctx, NROW, DIM, DIM, x, gate);
    k_gemm_f32<EPI_GELU>   <<<g1024, blk, 0, stream>>>(ctx, w1, b1, h1,   NROW, 2 * DIM, DIM, nullptr, nullptr);
    k_conv_wf              <<<GG,    blk, 0, stream>>>(wf, wf2);
    k_bias_c               <<<SS/4,  blk, 0, stream>>>(b2, wf2, cvec);
    k_gemm64<EPI_NONE, double><<<gW,    blk, 0, stream>>>(w2, wf2, nullptr, Wd,     1024, SS, GG);
    k_gemm64<EPI_BIAS, float> <<<g2048, blk, 0, stream>>>(h1, Wd,  cvec,    scores, NROW, SS, 2 * DIM);
    k_topk                 <<<NROW,  blk, 0, stream>>>(scores, sdr);
}

// Round 6
// 2042.798 us; speedup vs baseline: 1.7418x; 1.0868x over previous
//
#include <hip/hip_runtime.h>
#include <math.h>

// Problem constants
#define NROW 8192   // B*T
#define DIM  512
#define TT   2048
#define HH   4
#define DH   128
#define GG   2025   // GH*GW
#define SS   2048
#define KTOP 40

// ---------------------------------------------------------------------------
// embed gather + layernorm:  x = table[tok], xn = LN(x)*g + b
// ---------------------------------------------------------------------------
__global__ __launch_bounds__(256) void k_embed_ln(
    const int* __restrict__ tokens, const float* __restrict__ table,
    const float* __restrict__ g, const float* __restrict__ b,
    float* __restrict__ x, float* __restrict__ xn)
{
    __shared__ float red[4];
    const int row = blockIdx.x;
    const int tid = threadIdx.x;
    const float* src = table + (size_t)tokens[row] * DIM;
    float v0 = src[tid], v1 = src[tid + 256];

    float s = v0 + v1;
    for (int off = 32; off; off >>= 1) s += __shfl_xor(s, off, 64);
    if ((tid & 63) == 0) red[tid >> 6] = s;
    __syncthreads();
    float mean = (red[0] + red[1] + red[2] + red[3]) * (1.0f / 512.0f);
    __syncthreads();

    float d0 = v0 - mean, d1 = v1 - mean;
    float ss = d0 * d0 + d1 * d1;
    for (int off = 32; off; off >>= 1) ss += __shfl_xor(ss, off, 64);
    if ((tid & 63) == 0) red[tid >> 6] = ss;
    __syncthreads();
    float var = (red[0] + red[1] + red[2] + red[3]) * (1.0f / 512.0f);
    float rs = 1.0f / sqrtf(var + 1e-5f);

    size_t base = (size_t)row * DIM;
    x[base + tid]        = v0;
    x[base + tid + 256]  = v1;
    xn[base + tid]       = d0 * rs * g[tid] + b[tid];
    xn[base + tid + 256] = d1 * rs * g[tid + 256] + b[tid + 256];
}

// ---------------------------------------------------------------------------
// f32 GEMM  C = epi(A @ B + bias). A: MxK, B: KxN row-major.
// 128x128 tile, BK=16, 256 thr, 8x8/thread. (unchanged from round 4 - passed)
// ---------------------------------------------------------------------------
enum { EPI_BIAS = 0, EPI_SIGMOID = 1, EPI_GATERES = 2, EPI_GELU = 3, EPI_NONE = 4 };

template<int EPI>
__global__ __launch_bounds__(256) void k_gemm_f32(
    const float* __restrict__ A, const float* __restrict__ B,
    const float* __restrict__ bias, float* __restrict__ C,
    int M, int N, int K,
    const float* __restrict__ resid, const float* __restrict__ gate)
{
    __shared__ float As[16][132];   // [k][m]
    __shared__ float Bs[16][132];   // [k][n]
    const int tid = threadIdx.x;
    const int tx = tid & 15, ty = tid >> 4;
    const int bm = blockIdx.y * 128, bn = blockIdx.x * 128;
    float acc[8][8] = {};

    const int a_m = tid >> 2;
    const int a_c = (tid & 3) * 4;
    const int b_r = tid >> 5;
    const int b_n = (tid & 31) * 4;

    const float* Arow0 = A + (size_t)(bm + a_m) * K + a_c;
    const float* Arow1 = A + (size_t)(bm + a_m + 64) * K + a_c;
    const float* Brow0 = B + (size_t)b_r * N + bn + b_n;
    const float* Brow1 = B + (size_t)(b_r + 8) * N + bn + b_n;

    for (int k0 = 0; k0 < K; k0 += 16) {
        float4 av0 = *(const float4*)(Arow0 + k0);
        float4 av1 = *(const float4*)(Arow1 + k0);
        float4 bv0 = *(const float4*)(Brow0 + (size_t)k0 * N);
        float4 bv1 = *(const float4*)(Brow1 + (size_t)k0 * N);
        __syncthreads();
        As[a_c + 0][a_m] = av0.x; As[a_c + 1][a_m] = av0.y;
        As[a_c + 2][a_m] = av0.z; As[a_c + 3][a_m] = av0.w;
        As[a_c + 0][a_m + 64] = av1.x; As[a_c + 1][a_m + 64] = av1.y;
        As[a_c + 2][a_m + 64] = av1.z; As[a_c + 3][a_m + 64] = av1.w;
        *(float4*)&Bs[b_r][b_n]     = bv0;
        *(float4*)&Bs[b_r + 8][b_n] = bv1;
        __syncthreads();
#pragma unroll
        for (int kk = 0; kk < 16; ++kk) {
            float4 a0 = *(const float4*)&As[kk][ty * 4];
            float4 a1 = *(const float4*)&As[kk][64 + ty * 4];
            float4 b0 = *(const float4*)&Bs[kk][tx * 4];
            float4 b1 = *(const float4*)&Bs[kk][64 + tx * 4];
            float av[8] = {a0.x, a0.y, a0.z, a0.w, a1.x, a1.y, a1.z, a1.w};
            float bv[8] = {b0.x, b0.y, b0.z, b0.w, b1.x, b1.y, b1.z, b1.w};
#pragma unroll
            for (int i = 0; i < 8; ++i)
#pragma unroll
                for (int j = 0; j < 8; ++j)
                    acc[i][j] = fmaf(av[i], bv[j], acc[i][j]);
        }
    }

#pragma unroll
    for (int i = 0; i < 8; ++i) {
        int m = bm + 4 * ty + (i & 3) + (i >> 2) * 64;
#pragma unroll
        for (int half = 0; half < 2; ++half) {
            int n0 = bn + 4 * tx + half * 64;
            size_t idx = (size_t)m * N + n0;
            float4 o;
            float* oo = (float*)&o;
#pragma unroll
            for (int j = 0; j < 4; ++j) {
                float t = acc[i][half * 4 + j];
                if (EPI != EPI_NONE) t += bias[n0 + j];
                float r;
                if (EPI == EPI_SIGMOID)      r = 1.0f / (1.0f + expf(-t));
                else if (EPI == EPI_GATERES) r = resid[idx + j] + gate[idx + j] * t;
                else if (EPI == EPI_GELU)    r = 0.5f * t * (1.0f + erff(t * 0.70710678118654752440f));
                else                         r = t;
                oo[j] = r;
            }
            *(float4*)&C[idx] = o;
        }
    }
}

// ---------------------------------------------------------------------------
// f64 vector GEMM, register-blocked.  C = A(f32,MxK) @ B(f64,KxN) [+bias f64].
// 128x128 block tile, BK=16, 256 thr, 8x8 f64 per thread.
// Per-output K accumulation order = sequential k (stages x kk) -> bitwise
// identical to the round-3/4 kernels (which passed).
// LDS reads per kk: A 4x ds_read_b128 (2-way aliased = free, 16-lane
// broadcast); B 8x ds_read_b64 at cols tx+16j -> 16 distinct even banks,
// 4-lane broadcast, conflict-free. 64 f64 FMA per kk -> FMA-bound.
// Requires M%128==0, N%128==0; K ragged OK (zero-pad in staging).
// ---------------------------------------------------------------------------
template<int EPI, typename TC>
__global__ __launch_bounds__(256, 2) void k_gemm64v(
    const float* __restrict__ A, const double* __restrict__ B,
    const double* __restrict__ bias, TC* __restrict__ C,
    int M, int N, int K)
{
    __shared__ double As[16][130];   // [k][m], pad 130
    __shared__ double Bs[16][130];   // [k][n], pad 130
    const int tid = threadIdx.x;
    const int tx = tid & 15, ty = tid >> 4;          // thread -> (col, row) tile
    const int bm = blockIdx.y * 128, bn = blockIdx.x * 128;

    double acc[8][8] = {};

    // staging: A 128 rows x 16 k, thread: row=tid>>1, kbase=(tid&1)*8
    //          B 16 rows x 128 n, thread: row=tid&15, nbase=(tid>>4)*8
    const int ar  = tid >> 1,  akb = (tid & 1) * 8;
    const int brw = tid & 15,  bnb = (tid >> 4) * 8;

    const int nstage = (K + 15) / 16;
    for (int st = 0; st < nstage; ++st) {
        const int k0 = st * 16;
        double a_stage[8], b_stage[8];
        const float*  Ap = A + (size_t)(bm + ar) * K + k0 + akb;
        const double* Bp = B + (size_t)(k0 + brw) * N + bn + bnb;
        if (k0 + 16 <= K) {
#pragma unroll
            for (int j = 0; j < 8; ++j) a_stage[j] = (double)Ap[j];
#pragma unroll
            for (int j2 = 0; j2 < 4; ++j2) {
                double2 t = *(const double2*)(Bp + 2 * j2);
                b_stage[2 * j2] = t.x; b_stage[2 * j2 + 1] = t.y;
            }
        } else {
#pragma unroll
            for (int j = 0; j < 8; ++j)
                a_stage[j] = (k0 + akb + j < K) ? (double)Ap[j] : 0.0;
            bool brow_ok = (k0 + brw < K);
#pragma unroll
            for (int j = 0; j < 8; ++j)
                b_stage[j] = brow_ok ? Bp[j] : 0.0;
        }
        __syncthreads();                 // prev-stage LDS reads complete
#pragma unroll
        for (int j = 0; j < 8; ++j) As[akb + j][ar] = a_stage[j];
#pragma unroll
        for (int j = 0; j < 8; ++j) Bs[brw][bnb + j] = b_stage[j];
        __syncthreads();                 // tile ready
#pragma unroll
        for (int kk = 0; kk < 16; ++kk) {
            double av[8], bv[8];
#pragma unroll
            for (int i2 = 0; i2 < 4; ++i2) {
                double2 t = *(const double2*)&As[kk][ty * 8 + 2 * i2];
                av[2 * i2] = t.x; av[2 * i2 + 1] = t.y;
            }
#pragma unroll
            for (int j = 0; j < 8; ++j) bv[j] = Bs[kk][tx + 16 * j];
#pragma unroll
            for (int i = 0; i < 8; ++i)
#pragma unroll
                for (int j = 0; j < 8; ++j)
                    acc[i][j] = fma(av[i], bv[j], acc[i][j]);
        }
    }

#pragma unroll
    for (int i = 0; i < 8; ++i) {
        const int m = bm + ty * 8 + i;
#pragma unroll
        for (int j = 0; j < 8; ++j) {
            const int n = bn + tx + 16 * j;
            double t = acc[i][j];
            if (EPI == EPI_BIAS) t += bias[n];
            C[(size_t)m * N + n] = (TC)t;
        }
    }
}

// ---------------------------------------------------------------------------
// banded attention, window half-width 5 (W=11). One wave per (b,t,h).
// ---------------------------------------------------------------------------
__global__ __launch_bounds__(256) void k_attn(
    const float* __restrict__ q, const float* __restrict__ k,
    const float* __restrict__ v, float* __restrict__ out)
{
    const int w    = (blockIdx.x << 2) + (threadIdx.x >> 6);
    const int lane = threadIdx.x & 63;
    const int h = w & 3;
    const int t = (w >> 2) & 2047;
    const int b = w >> 13;
    const size_t rowbase = ((size_t)(b * TT + t)) * DIM + h * DH;
    const float q0 = q[rowbase + lane], q1 = q[rowbase + 64 + lane];

    float s[11];
#pragma unroll
    for (int o = 0; o < 11; ++o) {
        int pos = t + o - 5;
        bool valid = (pos >= 0 && pos < TT);
        float p = 0.0f;
        if (valid) {
            size_t kb = ((size_t)(b * TT + pos)) * DIM + h * DH;
            p = q0 * k[kb + lane] + q1 * k[kb + 64 + lane];
        }
        for (int off = 32; off; off >>= 1) p += __shfl_xor(p, off, 64);
        s[o] = valid ? p / sqrtf(128.0f) : -1e9f;
    }
    float m = s[0];
#pragma unroll
    for (int o = 1; o < 11; ++o) m = fmaxf(m, s[o]);
    float e[11], sum = 0.0f;
#pragma unroll
    for (int o = 0; o < 11; ++o) { e[o] = expf(s[o] - m); sum += e[o]; }

    float o0 = 0.0f, o1 = 0.0f;
#pragma unroll
    for (int o = 0; o < 11; ++o) {
        int pos = t + o - 5;
        if (pos < 0 || pos >= TT) continue;
        float a = e[o] / sum;
        size_t vb = ((size_t)(b * TT + pos)) * DIM + h * DH;
        o0 = fmaf(a, v[vb + lane], o0);
        o1 = fmaf(a, v[vb + 64 + lane], o1);
    }
    out[rowbase + lane]      = o0;
    out[rowbase + 64 + lane] = o1;
}

// ---------------------------------------------------------------------------
// wf2[q,s] = sum_p L[q,p] * wf[p,s]   (conv applied to wf's grid index)
// ---------------------------------------------------------------------------
__global__ __launch_bounds__(256) void k_conv_wf(
    const float* __restrict__ wf, double* __restrict__ wf2)
{
    __shared__ float w[25];
    const int qq = blockIdx.x;
    const int y = qq / 45, x = qq % 45;
    if (threadIdx.x < 25) {
        int ki = threadIdx.x / 5, kj = threadIdx.x % 5;
        double gi = exp(-0.5 * (double)((ki - 2) * (ki - 2)));
        double gj = exp(-0.5 * (double)((kj - 2) * (kj - 2)));
        double Z  = 1.0 + 2.0 * exp(-0.5) + 2.0 * exp(-2.0);
        w[threadIdx.x] = (float)(gi * gj / (Z * Z));
    }
    __syncthreads();
    for (int s = threadIdx.x; s < SS; s += 256) {
        double acc = 0.0;
#pragma unroll
        for (int dy = -2; dy <= 2; ++dy) {
            int yy = y + dy;
            if (yy < 0 || yy >= 45) continue;
#pragma unroll
            for (int dx = -2; dx <= 2; ++dx) {
                int xx2 = x + dx;
                if (xx2 < 0 || xx2 >= 45) continue;
                acc = fma((double)w[(dy + 2) * 5 + (dx + 2)],
                          (double)wf[(size_t)(yy * 45 + xx2) * SS + s], acc);
            }
        }
        wf2[(size_t)qq * SS + s] = acc;
    }
}

// c[s] = sum_q b2[q] * wf2[q,s]  — one wave per s, lane-strided + shfl reduce
__global__ __launch_bounds__(256) void k_bias_c(
    const float* __restrict__ b2, const double* __restrict__ wf2,
    double* __restrict__ c)
{
    const int s = blockIdx.x * 4 + (threadIdx.x >> 6);
    const int lane = threadIdx.x & 63;
    double acc = 0.0;
    for (int qq = lane; qq < GG; qq += 64)
        acc = fma((double)b2[qq], wf2[(size_t)qq * SS + s], acc);
    for (int off = 32; off; off >>= 1) acc += __shfl_xor(acc, off, 64);
    if (lane == 0) c[s] = acc;
}

// ---------------------------------------------------------------------------
// top-40 one-hot per row of 2048; iterative argmax, tie -> lower index
// ---------------------------------------------------------------------------
__global__ __launch_bounds__(256) void k_topk(
    const float* __restrict__ scores, float* __restrict__ sdr)
{
    __shared__ float vals[SS];
    __shared__ float rv[4];
    __shared__ int   ri[4];
    const int row = blockIdx.x;
    const float* srow = scores + (size_t)row * SS;
    float* drow = sdr + (size_t)row * SS;
    for (int i = threadIdx.x; i < SS; i += 256) { vals[i] = srow[i]; drow[i] = 0.0f; }
    __syncthreads();
    const int lane = threadIdx.x & 63, wid = threadIdx.x >> 6;
    for (int it = 0; it < KTOP; ++it) {
        float bv = -INFINITY; int bi = 0x7fffffff;
        for (int i = threadIdx.x; i < SS; i += 256) {
            float vv = vals[i];
            if (vv > bv) { bv = vv; bi = i; }
        }
        for (int off = 32; off; off >>= 1) {
            float ov = __shfl_xor(bv, off, 64);
            int   oi = __shfl_xor(bi, off, 64);
            if (ov > bv || (ov == bv && oi < bi)) { bv = ov; bi = oi; }
        }
        if (lane == 0) { rv[wid] = bv; ri[wid] = bi; }
        __syncthreads();
        if (threadIdx.x == 0) {
            float fv = rv[0]; int fi = ri[0];
            for (int wdx = 1; wdx < 4; ++wdx)
                if (rv[wdx] > fv || (rv[wdx] == fv && ri[wdx] < fi)) { fv = rv[wdx]; fi = ri[wdx]; }
            vals[fi] = -INFINITY;
            drow[fi] = 1.0f;
        }
        __syncthreads();
    }
}

// ---------------------------------------------------------------------------
// All intermediates inside d_out (same placement as rounds 3/4 - passed).
// ---------------------------------------------------------------------------
extern "C" void kernel_launch(void* const* d_in, const int* in_sizes, int n_in,
                              void* d_out, int out_size, void* d_ws, size_t ws_size,
                              hipStream_t stream)
{
    (void)d_ws; (void)ws_size; (void)in_sizes; (void)n_in; (void)out_size;

    const int*   tokens = (const int*)d_in[0];
    const float* table  = (const float*)d_in[1];
    const float* ln_g   = (const float*)d_in[2];
    const float* ln_b   = (const float*)d_in[3];
    const float* wq = (const float*)d_in[4];  const float* bq = (const float*)d_in[5];
    const float* wk = (const float*)d_in[6];  const float* bk = (const float*)d_in[7];
    const float* wv = (const float*)d_in[8];  const float* bv = (const float*)d_in[9];
    const float* wo = (const float*)d_in[10]; const float* bo = (const float*)d_in[11];
    const float* wg = (const float*)d_in[12]; const float* bg = (const float*)d_in[13];
    const float* w1 = (const float*)d_in[14]; const float* b1 = (const float*)d_in[15];
    const float* w2 = (const float*)d_in[16]; const float* b2 = (const float*)d_in[17];
    const float* wf = (const float*)d_in[18];

    const size_t SZ = (size_t)NROW * DIM;          // 4,194,304 floats
    float* slot0 = (float*)d_out;
    float* slot1 = slot0 + (size_t)NROW * SS;

    float* x    = slot0;
    float* attn = slot0 + SZ;
    float* ctx  = slot0 + 2 * SZ;
    float* xn   = slot0 + 3 * SZ;
    float* q    = slot1;
    float* kbuf = slot1 + SZ;
    float* vbuf = slot1 + 2 * SZ;
    float* gate = slot1 + 3 * SZ;
    float*  h1   = slot0;                                  // 8192x1024 f32
    double* wf2  = (double*)slot1;                         // 2025x2048 f64
    double* Wd   = (double*)(slot0 + 2 * SZ);              // 1024x2048 f64
    double* cvec = (double*)(slot0 + 4 * SZ - 4096);       // 2048 f64
    float* scores = slot1;
    float* sdr    = slot0;

    dim3 blk(256);
    dim3 g512(4, 64), g1024(8, 64);          // f32 GEMM: 128x128 tiles
    dim3 gW(16, 8), g2048(16, 64);           // f64 GEMM: 128x128 tiles

    k_embed_ln<<<NROW, blk, 0, stream>>>(tokens, table, ln_g, ln_b, x, xn);
    k_gemm_f32<EPI_BIAS>   <<<g512,  blk, 0, stream>>>(xn, wq, bq, q,    NROW, DIM, DIM, nullptr, nullptr);
    k_gemm_f32<EPI_BIAS>   <<<g512,  blk, 0, stream>>>(xn, wk, bk, kbuf, NROW, DIM, DIM, nullptr, nullptr);
    k_gemm_f32<EPI_BIAS>   <<<g512,  blk, 0, stream>>>(xn, wv, bv, vbuf, NROW, DIM, DIM, nullptr, nullptr);
    k_gemm_f32<EPI_SIGMOID><<<g512,  blk, 0, stream>>>(xn, wg, bg, gate, NROW, DIM, DIM, nullptr, nullptr);
    k_attn                 <<<NROW,  blk, 0, stream>>>(q, kbuf, vbuf, attn);
    k_gemm_f32<EPI_GATERES><<<g512,  blk, 0, stream>>>(attn, wo, bo, ctx, NROW, DIM, DIM, x, gate);
    k_gemm_f32<EPI_GELU>   <<<g1024, blk, 0, stream>>>(ctx, w1, b1, h1,   NROW, 2 * DIM, DIM, nullptr, nullptr);
    k_conv_wf              <<<GG,    blk, 0, stream>>>(wf, wf2);
    k_bias_c               <<<SS/4,  blk, 0, stream>>>(b2, wf2, cvec);
    k_gemm64v<EPI_NONE, double><<<gW,    blk, 0, stream>>>(w2, wf2, nullptr, Wd,     1024, SS, GG);
    k_gemm64v<EPI_BIAS, float> <<<g2048, blk, 0, stream>>>(h1, Wd,  cvec,    scores, NROW, SS, 2 * DIM);
    k_topk                 <<<NROW,  blk, 0, stream>>>(scores, sdr);
}

// Round 7
// 1515.990 us; speedup vs baseline: 2.3471x; 1.3475x over previous
//
#include <hip/hip_runtime.h>
#include <math.h>

// Problem constants
#define NROW 8192   // B*T
#define DIM  512
#define TT   2048
#define HH   4
#define DH   128
#define GG   2025   // GH*GW
#define GP   2032   // GG padded to %16
#define SS   2048
#define KTOP 40

// ---------------------------------------------------------------------------
// embed gather + layernorm:  x = table[tok], xn = LN(x)*g + b
// ---------------------------------------------------------------------------
__global__ __launch_bounds__(256) void k_embed_ln(
    const int* __restrict__ tokens, const float* __restrict__ table,
    const float* __restrict__ g, const float* __restrict__ b,
    float* __restrict__ x, float* __restrict__ xn)
{
    __shared__ float red[4];
    const int row = blockIdx.x;
    const int tid = threadIdx.x;
    const float* src = table + (size_t)tokens[row] * DIM;
    float v0 = src[tid], v1 = src[tid + 256];

    float s = v0 + v1;
    for (int off = 32; off; off >>= 1) s += __shfl_xor(s, off, 64);
    if ((tid & 63) == 0) red[tid >> 6] = s;
    __syncthreads();
    float mean = (red[0] + red[1] + red[2] + red[3]) * (1.0f / 512.0f);
    __syncthreads();

    float d0 = v0 - mean, d1 = v1 - mean;
    float ss = d0 * d0 + d1 * d1;
    for (int off = 32; off; off >>= 1) ss += __shfl_xor(ss, off, 64);
    if ((tid & 63) == 0) red[tid >> 6] = ss;
    __syncthreads();
    float var = (red[0] + red[1] + red[2] + red[3]) * (1.0f / 512.0f);
    float rs = 1.0f / sqrtf(var + 1e-5f);

    size_t base = (size_t)row * DIM;
    x[base + tid]        = v0;
    x[base + tid + 256]  = v1;
    xn[base + tid]       = d0 * rs * g[tid] + b[tid];
    xn[base + tid + 256] = d1 * rs * g[tid + 256] + b[tid + 256];
}

// ---------------------------------------------------------------------------
// f32 GEMM  C = epi(A @ B + bias). A: MxK, B: KxN row-major.
// 128x128 tile, BK=16, 256 thr, 8x8/thread. (proven rounds 4/6)
// Requires M%128==0, N%128==0, K%16==0, row strides %4==0.
// ---------------------------------------------------------------------------
enum { EPI_BIAS = 0, EPI_SIGMOID = 1, EPI_GATERES = 2, EPI_GELU = 3, EPI_NONE = 4 };

template<int EPI>
__global__ __launch_bounds__(256) void k_gemm_f32(
    const float* __restrict__ A, const float* __restrict__ B,
    const float* __restrict__ bias, float* __restrict__ C,
    int M, int N, int K,
    const float* __restrict__ resid, const float* __restrict__ gate)
{
    __shared__ float As[16][132];   // [k][m]
    __shared__ float Bs[16][132];   // [k][n]
    const int tid = threadIdx.x;
    const int tx = tid & 15, ty = tid >> 4;
    const int bm = blockIdx.y * 128, bn = blockIdx.x * 128;
    float acc[8][8] = {};

    const int a_m = tid >> 2;
    const int a_c = (tid & 3) * 4;
    const int b_r = tid >> 5;
    const int b_n = (tid & 31) * 4;

    const float* Arow0 = A + (size_t)(bm + a_m) * K + a_c;
    const float* Arow1 = A + (size_t)(bm + a_m + 64) * K + a_c;
    const float* Brow0 = B + (size_t)b_r * N + bn + b_n;
    const float* Brow1 = B + (size_t)(b_r + 8) * N + bn + b_n;

    for (int k0 = 0; k0 < K; k0 += 16) {
        float4 av0 = *(const float4*)(Arow0 + k0);
        float4 av1 = *(const float4*)(Arow1 + k0);
        float4 bv0 = *(const float4*)(Brow0 + (size_t)k0 * N);
        float4 bv1 = *(const float4*)(Brow1 + (size_t)k0 * N);
        __syncthreads();
        As[a_c + 0][a_m] = av0.x; As[a_c + 1][a_m] = av0.y;
        As[a_c + 2][a_m] = av0.z; As[a_c + 3][a_m] = av0.w;
        As[a_c + 0][a_m + 64] = av1.x; As[a_c + 1][a_m + 64] = av1.y;
        As[a_c + 2][a_m + 64] = av1.z; As[a_c + 3][a_m + 64] = av1.w;
        *(float4*)&Bs[b_r][b_n]     = bv0;
        *(float4*)&Bs[b_r + 8][b_n] = bv1;
        __syncthreads();
#pragma unroll
        for (int kk = 0; kk < 16; ++kk) {
            float4 a0 = *(const float4*)&As[kk][ty * 4];
            float4 a1 = *(const float4*)&As[kk][64 + ty * 4];
            float4 b0 = *(const float4*)&Bs[kk][tx * 4];
            float4 b1 = *(const float4*)&Bs[kk][64 + tx * 4];
            float av[8] = {a0.x, a0.y, a0.z, a0.w, a1.x, a1.y, a1.z, a1.w};
            float bv[8] = {b0.x, b0.y, b0.z, b0.w, b1.x, b1.y, b1.z, b1.w};
#pragma unroll
            for (int i = 0; i < 8; ++i)
#pragma unroll
                for (int j = 0; j < 8; ++j)
                    acc[i][j] = fmaf(av[i], bv[j], acc[i][j]);
        }
    }

#pragma unroll
    for (int i = 0; i < 8; ++i) {
        int m = bm + 4 * ty + (i & 3) + (i >> 2) * 64;
#pragma unroll
        for (int half = 0; half < 2; ++half) {
            int n0 = bn + 4 * tx + half * 64;
            size_t idx = (size_t)m * N + n0;
            float4 o;
            float* oo = (float*)&o;
#pragma unroll
            for (int j = 0; j < 4; ++j) {
                float t = acc[i][half * 4 + j];
                if (EPI != EPI_NONE) t += bias[n0 + j];
                float r;
                if (EPI == EPI_SIGMOID)      r = 1.0f / (1.0f + expf(-t));
                else if (EPI == EPI_GATERES) r = resid[idx + j] + gate[idx + j] * t;
                else if (EPI == EPI_GELU)    r = 0.5f * t * (1.0f + erff(t * 0.70710678118654752440f));
                else                         r = t;
                oo[j] = r;
            }
            *(float4*)&C[idx] = o;
        }
    }
}

// ---------------------------------------------------------------------------
// banded attention, window half-width 5 (W=11). One wave per (b,t,h).
// ---------------------------------------------------------------------------
__global__ __launch_bounds__(256) void k_attn(
    const float* __restrict__ q, const float* __restrict__ k,
    const float* __restrict__ v, float* __restrict__ out)
{
    const int w    = (blockIdx.x << 2) + (threadIdx.x >> 6);
    const int lane = threadIdx.x & 63;
    const int h = w & 3;
    const int t = (w >> 2) & 2047;
    const int b = w >> 13;
    const size_t rowbase = ((size_t)(b * TT + t)) * DIM + h * DH;
    const float q0 = q[rowbase + lane], q1 = q[rowbase + 64 + lane];

    float s[11];
#pragma unroll
    for (int o = 0; o < 11; ++o) {
        int pos = t + o - 5;
        bool valid = (pos >= 0 && pos < TT);
        float p = 0.0f;
        if (valid) {
            size_t kb = ((size_t)(b * TT + pos)) * DIM + h * DH;
            p = q0 * k[kb + lane] + q1 * k[kb + 64 + lane];
        }
        for (int off = 32; off; off >>= 1) p += __shfl_xor(p, off, 64);
        s[o] = valid ? p / sqrtf(128.0f) : -1e9f;
    }
    float m = s[0];
#pragma unroll
    for (int o = 1; o < 11; ++o) m = fmaxf(m, s[o]);
    float e[11], sum = 0.0f;
#pragma unroll
    for (int o = 0; o < 11; ++o) { e[o] = expf(s[o] - m); sum += e[o]; }

    float o0 = 0.0f, o1 = 0.0f;
#pragma unroll
    for (int o = 0; o < 11; ++o) {
        int pos = t + o - 5;
        if (pos < 0 || pos >= TT) continue;
        float a = e[o] / sum;
        size_t vb = ((size_t)(b * TT + pos)) * DIM + h * DH;
        o0 = fmaf(a, v[vb + lane], o0);
        o1 = fmaf(a, v[vb + 64 + lane], o1);
    }
    out[rowbase + lane]      = o0;
    out[rowbase + 64 + lane] = o1;
}

// ---------------------------------------------------------------------------
// wf2f[q,s] = sum_p L[q,p] * wf[p,s]  (f64 accumulate, f32 out)
// grid GP blocks; rows GG..GP-1 zero-padded for the K%16 GEMM.
// ---------------------------------------------------------------------------
__global__ __launch_bounds__(256) void k_conv_wf(
    const float* __restrict__ wf, float* __restrict__ wf2f)
{
    __shared__ float w[25];
    const int qq = blockIdx.x;
    if (qq >= GG) {
        for (int s = threadIdx.x; s < SS; s += 256)
            wf2f[(size_t)qq * SS + s] = 0.0f;
        return;
    }
    const int y = qq / 45, x = qq % 45;
    if (threadIdx.x < 25) {
        int ki = threadIdx.x / 5, kj = threadIdx.x % 5;
        double gi = exp(-0.5 * (double)((ki - 2) * (ki - 2)));
        double gj = exp(-0.5 * (double)((kj - 2) * (kj - 2)));
        double Z  = 1.0 + 2.0 * exp(-0.5) + 2.0 * exp(-2.0);
        w[threadIdx.x] = (float)(gi * gj / (Z * Z));
    }
    __syncthreads();
    for (int s = threadIdx.x; s < SS; s += 256) {
        double acc = 0.0;
#pragma unroll
        for (int dy = -2; dy <= 2; ++dy) {
            int yy = y + dy;
            if (yy < 0 || yy >= 45) continue;
#pragma unroll
            for (int dx = -2; dx <= 2; ++dx) {
                int xx2 = x + dx;
                if (xx2 < 0 || xx2 >= 45) continue;
                acc = fma((double)w[(dy + 2) * 5 + (dx + 2)],
                          (double)wf[(size_t)(yy * 45 + xx2) * SS + s], acc);
            }
        }
        wf2f[(size_t)qq * SS + s] = (float)acc;
    }
}

// w2pad[m][p] = p < GG ? w2[m][p] : 0   (1024 x GP)
__global__ __launch_bounds__(256) void k_pad_w2(
    const float* __restrict__ w2, float* __restrict__ w2pad)
{
    const size_t idx = (size_t)blockIdx.x * 256 + threadIdx.x;
    if (idx >= (size_t)1024 * GP) return;
    const int m = (int)(idx / GP), p = (int)(idx % GP);
    w2pad[idx] = (p < GG) ? w2[(size_t)m * GG + p] : 0.0f;
}

// c[s] = sum_q b2[q] * wf2f[q,s]  (f64 accumulate, f32 out)
__global__ __launch_bounds__(256) void k_bias_c(
    const float* __restrict__ b2, const float* __restrict__ wf2f,
    float* __restrict__ c)
{
    const int s = blockIdx.x * 4 + (threadIdx.x >> 6);
    const int lane = threadIdx.x & 63;
    double acc = 0.0;
    for (int qq = lane; qq < GG; qq += 64)
        acc = fma((double)b2[qq], (double)wf2f[(size_t)qq * SS + s], acc);
    for (int off = 32; off; off >>= 1) acc += __shfl_xor(acc, off, 64);
    if (lane == 0) c[s] = (float)acc;
}

// ---------------------------------------------------------------------------
// top-40 one-hot per row of 2048; iterative argmax, tie -> lower index
// ---------------------------------------------------------------------------
__global__ __launch_bounds__(256) void k_topk(
    const float* __restrict__ scores, float* __restrict__ sdr)
{
    __shared__ float vals[SS];
    __shared__ float rv[4];
    __shared__ int   ri[4];
    const int row = blockIdx.x;
    const float* srow = scores + (size_t)row * SS;
    float* drow = sdr + (size_t)row * SS;
    for (int i = threadIdx.x; i < SS; i += 256) { vals[i] = srow[i]; drow[i] = 0.0f; }
    __syncthreads();
    const int lane = threadIdx.x & 63, wid = threadIdx.x >> 6;
    for (int it = 0; it < KTOP; ++it) {
        float bv = -INFINITY; int bi = 0x7fffffff;
        for (int i = threadIdx.x; i < SS; i += 256) {
            float vv = vals[i];
            if (vv > bv) { bv = vv; bi = i; }
        }
        for (int off = 32; off; off >>= 1) {
            float ov = __shfl_xor(bv, off, 64);
            int   oi = __shfl_xor(bi, off, 64);
            if (ov > bv || (ov == bv && oi < bi)) { bv = ov; bi = oi; }
        }
        if (lane == 0) { rv[wid] = bv; ri[wid] = bi; }
        __syncthreads();
        if (threadIdx.x == 0) {
            float fv = rv[0]; int fi = ri[0];
            for (int wdx = 1; wdx < 4; ++wdx)
                if (rv[wdx] > fv || (rv[wdx] == fv && ri[wdx] < fi)) { fv = rv[wdx]; fi = ri[wdx]; }
            vals[fi] = -INFINITY;
            drow[fi] = 1.0f;
        }
        __syncthreads();
    }
}

// ---------------------------------------------------------------------------
// Buffer plan (all inside d_out; slot0/slot1 = 16,777,216 floats each):
//  1 embed_ln  -> x@s0+0, xn@s0+3SZ
//  2 q,k,v,gate GEMM -> s1+{0,SZ,2SZ,3SZ}
//  3 attn      -> attn@s0+SZ            (q,k dead)
//  4 gateres   -> ctx@s0+2SZ            (x,gate dead)
//  5 gelu      -> h1@s0+0..2SZ          (reads ctx; x,attn overwritten-dead)
//  6 conv_wf   -> wf2f@s1+0  (GPx2048=4.16M < SZ; over dead q)
//  7 pad_w2    -> w2pad@s1+SZ (1024xGP=2.08M; over dead k)
//  8 bias_c    -> cvec@s0+3SZ (xn dead)
//  9 W GEMM    -> Wf@s0+2SZ  (1024x2048=2.1M; ctx dead)
// 10 scores GEMM (h1@s0, Wf@s0, cvec@s0) -> scores@s1 (all of s1 dead)
// 11 topk      -> sdr@s0
// ---------------------------------------------------------------------------
extern "C" void kernel_launch(void* const* d_in, const int* in_sizes, int n_in,
                              void* d_out, int out_size, void* d_ws, size_t ws_size,
                              hipStream_t stream)
{
    (void)d_ws; (void)ws_size; (void)in_sizes; (void)n_in; (void)out_size;

    const int*   tokens = (const int*)d_in[0];
    const float* table  = (const float*)d_in[1];
    const float* ln_g   = (const float*)d_in[2];
    const float* ln_b   = (const float*)d_in[3];
    const float* wq = (const float*)d_in[4];  const float* bq = (const float*)d_in[5];
    const float* wk = (const float*)d_in[6];  const float* bk = (const float*)d_in[7];
    const float* wv = (const float*)d_in[8];  const float* bv = (const float*)d_in[9];
    const float* wo = (const float*)d_in[10]; const float* bo = (const float*)d_in[11];
    const float* wg = (const float*)d_in[12]; const float* bg = (const float*)d_in[13];
    const float* w1 = (const float*)d_in[14]; const float* b1 = (const float*)d_in[15];
    const float* w2 = (const float*)d_in[16]; const float* b2 = (const float*)d_in[17];
    const float* wf = (const float*)d_in[18];

    const size_t SZ = (size_t)NROW * DIM;          // 4,194,304 floats
    float* slot0 = (float*)d_out;
    float* slot1 = slot0 + (size_t)NROW * SS;

    float* x    = slot0;
    float* attn = slot0 + SZ;
    float* ctx  = slot0 + 2 * SZ;
    float* xn   = slot0 + 3 * SZ;
    float* q    = slot1;
    float* kbuf = slot1 + SZ;
    float* vbuf = slot1 + 2 * SZ;
    float* gate = slot1 + 3 * SZ;
    float* h1    = slot0;                      // 8192x1024
    float* wf2f  = slot1;                      // GPx2048
    float* w2pad = slot1 + SZ;                 // 1024xGP
    float* Wf    = slot0 + 2 * SZ;             // 1024x2048
    float* cvec  = slot0 + 3 * SZ;             // 2048
    float* scores = slot1;
    float* sdr    = slot0;

    dim3 blk(256);
    dim3 g512(4, 64), g1024(8, 64), gW(16, 8), g2048(16, 64);

    k_embed_ln<<<NROW, blk, 0, stream>>>(tokens, table, ln_g, ln_b, x, xn);
    k_gemm_f32<EPI_BIAS>   <<<g512,  blk, 0, stream>>>(xn, wq, bq, q,    NROW, DIM, DIM, nullptr, nullptr);
    k_gemm_f32<EPI_BIAS>   <<<g512,  blk, 0, stream>>>(xn, wk, bk, kbuf, NROW, DIM, DIM, nullptr, nullptr);
    k_gemm_f32<EPI_BIAS>   <<<g512,  blk, 0, stream>>>(xn, wv, bv, vbuf, NROW, DIM, DIM, nullptr, nullptr);
    k_gemm_f32<EPI_SIGMOID><<<g512,  blk, 0, stream>>>(xn, wg, bg, gate, NROW, DIM, DIM, nullptr, nullptr);
    k_attn                 <<<NROW,  blk, 0, stream>>>(q, kbuf, vbuf, attn);
    k_gemm_f32<EPI_GATERES><<<g512,  blk, 0, stream>>>(attn, wo, bo, ctx, NROW, DIM, DIM, x, gate);
    k_gemm_f32<EPI_GELU>   <<<g1024, blk, 0, stream>>>(ctx, w1, b1, h1,   NROW, 2 * DIM, DIM, nullptr, nullptr);
    k_conv_wf              <<<GP,    blk, 0, stream>>>(wf, wf2f);
    k_pad_w2               <<<(1024 * GP + 255) / 256, blk, 0, stream>>>(w2, w2pad);
    k_bias_c               <<<SS/4,  blk, 0, stream>>>(b2, wf2f, cvec);
    k_gemm_f32<EPI_NONE>   <<<gW,    blk, 0, stream>>>(w2pad, wf2f, nullptr, Wf, 1024, SS, GP, nullptr, nullptr);
    k_gemm_f32<EPI_BIAS>   <<<g2048, blk, 0, stream>>>(h1, Wf, cvec, scores, NROW, SS, 2 * DIM, nullptr, nullptr);
    k_topk                 <<<NROW,  blk, 0, stream>>>(scores, sdr);
}

// Round 10
// 1504.850 us; speedup vs baseline: 2.3645x; 1.0074x over previous
//
#include <hip/hip_runtime.h>
#include <math.h>

// Problem constants
#define NROW 8192   // B*T
#define DIM  512
#define TT   2048
#define HH   4
#define DH   128
#define GG   2025   // GH*GW
#define GP   2032   // GG padded to %16
#define SS   2048
#define KTOP 40

// ---------------------------------------------------------------------------
// embed gather + layernorm:  x = table[tok], xn = LN(x)*g + b
// ---------------------------------------------------------------------------
__global__ __launch_bounds__(256) void k_embed_ln(
    const int* __restrict__ tokens, const float* __restrict__ table,
    const float* __restrict__ g, const float* __restrict__ b,
    float* __restrict__ x, float* __restrict__ xn)
{
    __shared__ float red[4];
    const int row = blockIdx.x;
    const int tid = threadIdx.x;
    const float* src = table + (size_t)tokens[row] * DIM;
    float v0 = src[tid], v1 = src[tid + 256];

    float s = v0 + v1;
    for (int off = 32; off; off >>= 1) s += __shfl_xor(s, off, 64);
    if ((tid & 63) == 0) red[tid >> 6] = s;
    __syncthreads();
    float mean = (red[0] + red[1] + red[2] + red[3]) * (1.0f / 512.0f);
    __syncthreads();

    float d0 = v0 - mean, d1 = v1 - mean;
    float ss = d0 * d0 + d1 * d1;
    for (int off = 32; off; off >>= 1) ss += __shfl_xor(ss, off, 64);
    if ((tid & 63) == 0) red[tid >> 6] = ss;
    __syncthreads();
    float var = (red[0] + red[1] + red[2] + red[3]) * (1.0f / 512.0f);
    float rs = 1.0f / sqrtf(var + 1e-5f);

    size_t base = (size_t)row * DIM;
    x[base + tid]        = v0;
    x[base + tid + 256]  = v1;
    xn[base + tid]       = d0 * rs * g[tid] + b[tid];
    xn[base + tid + 256] = d1 * rs * g[tid + 256] + b[tid + 256];
}

// ---------------------------------------------------------------------------
// f32 GEMM  C = epi(A @ B + bias). A: MxK, B: KxN row-major.
// 128x128 tile, BK=16, 256 thr, 8x8/thread. (proven rounds 4/6/7)
// KCH>0: split-K — blockIdx.z handles [z*KCH, min(+KCH,K)), writes partial
// to C + z*M*N with no epilogue. KCH=0 codegen-identical to round 7.
// ---------------------------------------------------------------------------
enum { EPI_BIAS = 0, EPI_SIGMOID = 1, EPI_GATERES = 2, EPI_GELU = 3, EPI_NONE = 4 };

template<int EPI, int KCH = 0>
__global__ __launch_bounds__(256) void k_gemm_f32(
    const float* __restrict__ A, const float* __restrict__ B,
    const float* __restrict__ bias, float* __restrict__ C,
    int M, int N, int K,
    const float* __restrict__ resid, const float* __restrict__ gate)
{
    __shared__ float As[16][132];   // [k][m]
    __shared__ float Bs[16][132];   // [k][n]
    const int tid = threadIdx.x;
    const int tx = tid & 15, ty = tid >> 4;
    const int bm = blockIdx.y * 128, bn = blockIdx.x * 128;
    float acc[8][8] = {};

    int kbeg = 0, kend = K;
    float* Cw = C;
    if (KCH > 0) {
        kbeg = blockIdx.z * KCH;
        kend = min(kbeg + KCH, K);
        Cw = C + (size_t)blockIdx.z * M * N;
    }

    const int a_m = tid >> 2;
    const int a_c = (tid & 3) * 4;
    const int b_r = tid >> 5;
    const int b_n = (tid & 31) * 4;

    const float* Arow0 = A + (size_t)(bm + a_m) * K + a_c;
    const float* Arow1 = A + (size_t)(bm + a_m + 64) * K + a_c;
    const float* Brow0 = B + (size_t)b_r * N + bn + b_n;
    const float* Brow1 = B + (size_t)(b_r + 8) * N + bn + b_n;

    for (int k0 = kbeg; k0 < kend; k0 += 16) {
        float4 av0 = *(const float4*)(Arow0 + k0);
        float4 av1 = *(const float4*)(Arow1 + k0);
        float4 bv0 = *(const float4*)(Brow0 + (size_t)k0 * N);
        float4 bv1 = *(const float4*)(Brow1 + (size_t)k0 * N);
        __syncthreads();
        As[a_c + 0][a_m] = av0.x; As[a_c + 1][a_m] = av0.y;
        As[a_c + 2][a_m] = av0.z; As[a_c + 3][a_m] = av0.w;
        As[a_c + 0][a_m + 64] = av1.x; As[a_c + 1][a_m + 64] = av1.y;
        As[a_c + 2][a_m + 64] = av1.z; As[a_c + 3][a_m + 64] = av1.w;
        *(float4*)&Bs[b_r][b_n]     = bv0;
        *(float4*)&Bs[b_r + 8][b_n] = bv1;
        __syncthreads();
#pragma unroll
        for (int kk = 0; kk < 16; ++kk) {
            float4 a0 = *(const float4*)&As[kk][ty * 4];
            float4 a1 = *(const float4*)&As[kk][64 + ty * 4];
            float4 b0 = *(const float4*)&Bs[kk][tx * 4];
            float4 b1 = *(const float4*)&Bs[kk][64 + tx * 4];
            float av[8] = {a0.x, a0.y, a0.z, a0.w, a1.x, a1.y, a1.z, a1.w};
            float bv[8] = {b0.x, b0.y, b0.z, b0.w, b1.x, b1.y, b1.z, b1.w};
#pragma unroll
            for (int i = 0; i < 8; ++i)
#pragma unroll
                for (int j = 0; j < 8; ++j)
                    acc[i][j] = fmaf(av[i], bv[j], acc[i][j]);
        }
    }

#pragma unroll
    for (int i = 0; i < 8; ++i) {
        int m = bm + 4 * ty + (i & 3) + (i >> 2) * 64;
#pragma unroll
        for (int half = 0; half < 2; ++half) {
            int n0 = bn + 4 * tx + half * 64;
            size_t idx = (size_t)m * N + n0;
            float4 o;
            float* oo = (float*)&o;
#pragma unroll
            for (int j = 0; j < 4; ++j) {
                float t = acc[i][half * 4 + j];
                if (EPI != EPI_NONE && KCH == 0) t += bias[n0 + j];
                float r;
                if (KCH > 0)                 r = t;
                else if (EPI == EPI_SIGMOID) r = 1.0f / (1.0f + expf(-t));
                else if (EPI == EPI_GATERES) r = resid[idx + j] + gate[idx + j] * t;
                else if (EPI == EPI_GELU)    r = 0.5f * t * (1.0f + erff(t * 0.70710678118654752440f));
                else                         r = t;
                oo[j] = r;
            }
            *(float4*)&Cw[idx] = o;
        }
    }
}

// ---------------------------------------------------------------------------
// f32 GEMM, 256x128 tile, BK=16, 256 thr, 16x8/thread. VALU-bound variant
// (96 B LDS per 128 FMAs vs 64 B per 64). Per-output k-order identical to
// k_gemm_f32 -> bitwise-same results. Requires M%256==0, N%128==0, K%16==0.
// ---------------------------------------------------------------------------
template<int EPI>
__global__ __launch_bounds__(256, 2) void k_gemm_f32_big(
    const float* __restrict__ A, const float* __restrict__ B,
    const float* __restrict__ bias, float* __restrict__ C,
    int M, int N, int K)
{
    __shared__ float As[16][260];   // [k][m]  (256 + pad 4)
    __shared__ float Bs[16][132];   // [k][n]
    const int tid = threadIdx.x;
    const int tx = tid & 15, ty = tid >> 4;
    const int bm = blockIdx.y * 256, bn = blockIdx.x * 128;
    float acc[16][8] = {};

    const int a_m = tid >> 2;          // 0..63 (also +64,+128,+192)
    const int a_c = (tid & 3) * 4;     // k-offset {0,4,8,12}
    const int b_r = tid >> 5;          // 0..7  (also +8)
    const int b_n = (tid & 31) * 4;

    const float* Br0 = B + (size_t)b_r * N + bn + b_n;
    const float* Br1 = B + (size_t)(b_r + 8) * N + bn + b_n;

    for (int k0 = 0; k0 < K; k0 += 16) {
        float4 av[4];
#pragma unroll
        for (int q = 0; q < 4; ++q)
            av[q] = *(const float4*)(A + (size_t)(bm + a_m + 64 * q) * K + k0 + a_c);
        float4 bv0 = *(const float4*)(Br0 + (size_t)k0 * N);
        float4 bv1 = *(const float4*)(Br1 + (size_t)k0 * N);
        __syncthreads();
#pragma unroll
        for (int q = 0; q < 4; ++q) {
            As[a_c + 0][a_m + 64 * q] = av[q].x;
            As[a_c + 1][a_m + 64 * q] = av[q].y;
            As[a_c + 2][a_m + 64 * q] = av[q].z;
            As[a_c + 3][a_m + 64 * q] = av[q].w;
        }
        *(float4*)&Bs[b_r][b_n]     = bv0;
        *(float4*)&Bs[b_r + 8][b_n] = bv1;
        __syncthreads();
#pragma unroll
        for (int kk = 0; kk < 16; ++kk) {
            float am[16], bn_[8];
#pragma unroll
            for (int q = 0; q < 4; ++q) {
                float4 t = *(const float4*)&As[kk][ty * 4 + 64 * q];
                am[q * 4 + 0] = t.x; am[q * 4 + 1] = t.y;
                am[q * 4 + 2] = t.z; am[q * 4 + 3] = t.w;
            }
            float4 u0 = *(const float4*)&Bs[kk][tx * 4];
            float4 u1 = *(const float4*)&Bs[kk][64 + tx * 4];
            bn_[0] = u0.x; bn_[1] = u0.y; bn_[2] = u0.z; bn_[3] = u0.w;
            bn_[4] = u1.x; bn_[5] = u1.y; bn_[6] = u1.z; bn_[7] = u1.w;
#pragma unroll
            for (int i = 0; i < 16; ++i)
#pragma unroll
                for (int j = 0; j < 8; ++j)
                    acc[i][j] = fmaf(am[i], bn_[j], acc[i][j]);
        }
    }

#pragma unroll
    for (int i = 0; i < 16; ++i) {
        int m = bm + 4 * ty + (i & 3) + (i >> 2) * 64;
#pragma unroll
        for (int half = 0; half < 2; ++half) {
            int n0 = bn + 4 * tx + half * 64;
            size_t idx = (size_t)m * N + n0;
            float4 o;
            float* oo = (float*)&o;
#pragma unroll
            for (int j = 0; j < 4; ++j) {
                float t = acc[i][half * 4 + j];
                if (EPI != EPI_NONE) t += bias[n0 + j];
                float r;
                if (EPI == EPI_GELU) r = 0.5f * t * (1.0f + erff(t * 0.70710678118654752440f));
                else                 r = t;
                oo[j] = r;
            }
            *(float4*)&C[idx] = o;
        }
    }
}

// Wf[i] = p0+p1+p2+p3 (float4-wide), in place over p0
__global__ __launch_bounds__(256) void k_add4(float4* __restrict__ p, int n4)
{
    const int i = blockIdx.x * 256 + threadIdx.x;
    if (i >= n4) return;
    float4 a = p[i], b = p[i + n4], c = p[i + 2 * n4], d = p[i + 3 * n4];
    a.x += b.x + c.x + d.x; a.y += b.y + c.y + d.y;
    a.z += b.z + c.z + d.z; a.w += b.w + c.w + d.w;
    p[i] = a;
}

// ---------------------------------------------------------------------------
// banded attention, window half-width 5 (W=11). One wave per (b,t,h).
// ---------------------------------------------------------------------------
__global__ __launch_bounds__(256) void k_attn(
    const float* __restrict__ q, const float* __restrict__ k,
    const float* __restrict__ v, float* __restrict__ out)
{
    const int w    = (blockIdx.x << 2) + (threadIdx.x >> 6);
    const int lane = threadIdx.x & 63;
    const int h = w & 3;
    const int t = (w >> 2) & 2047;
    const int b = w >> 13;
    const size_t rowbase = ((size_t)(b * TT + t)) * DIM + h * DH;
    const float q0 = q[rowbase + lane], q1 = q[rowbase + 64 + lane];

    float s[11];
#pragma unroll
    for (int o = 0; o < 11; ++o) {
        int pos = t + o - 5;
        bool valid = (pos >= 0 && pos < TT);
        float p = 0.0f;
        if (valid) {
            size_t kb = ((size_t)(b * TT + pos)) * DIM + h * DH;
            p = q0 * k[kb + lane] + q1 * k[kb + 64 + lane];
        }
        for (int off = 32; off; off >>= 1) p += __shfl_xor(p, off, 64);
        s[o] = valid ? p / sqrtf(128.0f) : -1e9f;
    }
    float m = s[0];
#pragma unroll
    for (int o = 1; o < 11; ++o) m = fmaxf(m, s[o]);
    float e[11], sum = 0.0f;
#pragma unroll
    for (int o = 0; o < 11; ++o) { e[o] = expf(s[o] - m); sum += e[o]; }

    float o0 = 0.0f, o1 = 0.0f;
#pragma unroll
    for (int o = 0; o < 11; ++o) {
        int pos = t + o - 5;
        if (pos < 0 || pos >= TT) continue;
        float a = e[o] / sum;
        size_t vb = ((size_t)(b * TT + pos)) * DIM + h * DH;
        o0 = fmaf(a, v[vb + lane], o0);
        o1 = fmaf(a, v[vb + 64 + lane], o1);
    }
    out[rowbase + lane]      = o0;
    out[rowbase + 64 + lane] = o1;
}

// ---------------------------------------------------------------------------
// wf2f[q,s] = sum_p L[q,p] * wf[p,s]  (f64 accumulate, f32 out; GP rows)
// ---------------------------------------------------------------------------
__global__ __launch_bounds__(256) void k_conv_wf(
    const float* __restrict__ wf, float* __restrict__ wf2f)
{
    __shared__ float w[25];
    const int qq = blockIdx.x;
    if (qq >= GG) {
        for (int s = threadIdx.x; s < SS; s += 256)
            wf2f[(size_t)qq * SS + s] = 0.0f;
        return;
    }
    const int y = qq / 45, x = qq % 45;
    if (threadIdx.x < 25) {
        int ki = threadIdx.x / 5, kj = threadIdx.x % 5;
        double gi = exp(-0.5 * (double)((ki - 2) * (ki - 2)));
        double gj = exp(-0.5 * (double)((kj - 2) * (kj - 2)));
        double Z  = 1.0 + 2.0 * exp(-0.5) + 2.0 * exp(-2.0);
        w[threadIdx.x] = (float)(gi * gj / (Z * Z));
    }
    __syncthreads();
    for (int s = threadIdx.x; s < SS; s += 256) {
        double acc = 0.0;
#pragma unroll
        for (int dy = -2; dy <= 2; ++dy) {
            int yy = y + dy;
            if (yy < 0 || yy >= 45) continue;
#pragma unroll
            for (int dx = -2; dx <= 2; ++dx) {
                int xx2 = x + dx;
                if (xx2 < 0 || xx2 >= 45) continue;
                acc = fma((double)w[(dy + 2) * 5 + (dx + 2)],
                          (double)wf[(size_t)(yy * 45 + xx2) * SS + s], acc);
            }
        }
        wf2f[(size_t)qq * SS + s] = (float)acc;
    }
}

// w2pad[m][p] = p < GG ? w2[m][p] : 0   (1024 x GP)
__global__ __launch_bounds__(256) void k_pad_w2(
    const float* __restrict__ w2, float* __restrict__ w2pad)
{
    const size_t idx = (size_t)blockIdx.x * 256 + threadIdx.x;
    if (idx >= (size_t)1024 * GP) return;
    const int m = (int)(idx / GP), p = (int)(idx % GP);
    w2pad[idx] = (p < GG) ? w2[(size_t)m * GG + p] : 0.0f;
}

// c[s] = sum_q b2[q] * wf2f[q,s]  (f64 accumulate, f32 out)
__global__ __launch_bounds__(256) void k_bias_c(
    const float* __restrict__ b2, const float* __restrict__ wf2f,
    float* __restrict__ c)
{
    const int s = blockIdx.x * 4 + (threadIdx.x >> 6);
    const int lane = threadIdx.x & 63;
    double acc = 0.0;
    for (int qq = lane; qq < GG; qq += 64)
        acc = fma((double)b2[qq], (double)wf2f[(size_t)qq * SS + s], acc);
    for (int off = 32; off; off >>= 1) acc += __shfl_xor(acc, off, 64);
    if (lane == 0) c[s] = (float)acc;
}

// ---------------------------------------------------------------------------
// top-40 one-hot per row of 2048; iterative argmax, tie -> lower index
// ---------------------------------------------------------------------------
__global__ __launch_bounds__(256) void k_topk(
    const float* __restrict__ scores, float* __restrict__ sdr)
{
    __shared__ float vals[SS];
    __shared__ float rv[4];
    __shared__ int   ri[4];
    const int row = blockIdx.x;
    const float* srow = scores + (size_t)row * SS;
    float* drow = sdr + (size_t)row * SS;
    for (int i = threadIdx.x; i < SS; i += 256) { vals[i] = srow[i]; drow[i] = 0.0f; }
    __syncthreads();
    const int lane = threadIdx.x & 63, wid = threadIdx.x >> 6;
    for (int it = 0; it < KTOP; ++it) {
        float bv = -INFINITY; int bi = 0x7fffffff;
        for (int i = threadIdx.x; i < SS; i += 256) {
            float vv = vals[i];
            if (vv > bv) { bv = vv; bi = i; }
        }
        for (int off = 32; off; off >>= 1) {
            float ov = __shfl_xor(bv, off, 64);
            int   oi = __shfl_xor(bi, off, 64);
            if (ov > bv || (ov == bv && oi < bi)) { bv = ov; bi = oi; }
        }
        if (lane == 0) { rv[wid] = bv; ri[wid] = bi; }
        __syncthreads();
        if (threadIdx.x == 0) {
            float fv = rv[0]; int fi = ri[0];
            for (int wdx = 1; wdx < 4; ++wdx)
                if (rv[wdx] > fv || (rv[wdx] == fv && ri[wdx] < fi)) { fv = rv[wdx]; fi = ri[wdx]; }
            vals[fi] = -INFINITY;
            drow[fi] = 1.0f;
        }
        __syncthreads();
    }
}

// ---------------------------------------------------------------------------
// Buffer plan (all inside d_out; slot0/slot1 = 16,777,216 floats each):
//  1 embed_ln -> x@s0+0, xn@s0+3SZ
//  2 qkvg GEMM -> s1+{0,SZ,2SZ,3SZ}
//  3 attn -> attn@s0+SZ (q,k dead)
//  4 gateres -> ctx@s0+2SZ (x,gate dead)
//  5 gelu (big) -> h1@s0[0..2SZ) (reads ctx)
//  6 conv_wf -> wf2f@s1[0..GP*SS) (q dead); 7 pad_w2 -> w2pad@s1+SZ (k dead)
//  8 W splitK x4 -> Wp@s0[2SZ..4SZ) exactly (ctx,xn dead)
//  9 add4 -> Wf@s0[2SZ..2SZ+2M)
// 10 bias_c -> cvec@s0+3SZ (over dead partial; reads wf2f intact)
// 11 scores (big) reads h1, Wf, cvec (all s0) -> scores@s1 (s1 all dead)
// 12 topk -> sdr@s0
// ---------------------------------------------------------------------------
extern "C" void kernel_launch(void* const* d_in, const int* in_sizes, int n_in,
                              void* d_out, int out_size, void* d_ws, size_t ws_size,
                              hipStream_t stream)
{
    (void)d_ws; (void)ws_size; (void)in_sizes; (void)n_in; (void)out_size;

    const int*   tokens = (const int*)d_in[0];
    const float* table  = (const float*)d_in[1];
    const float* ln_g   = (const float*)d_in[2];
    const float* ln_b   = (const float*)d_in[3];
    const float* wq = (const float*)d_in[4];  const float* bq = (const float*)d_in[5];
    const float* wk = (const float*)d_in[6];  const float* bk = (const float*)d_in[7];
    const float* wv = (const float*)d_in[8];  const float* bv = (const float*)d_in[9];
    const float* wo = (const float*)d_in[10]; const float* bo = (const float*)d_in[11];
    const float* wg = (const float*)d_in[12]; const float* bg = (const float*)d_in[13];
    const float* w1 = (const float*)d_in[14]; const float* b1 = (const float*)d_in[15];
    const float* w2 = (const float*)d_in[16]; const float* b2 = (const float*)d_in[17];
    const float* wf = (const float*)d_in[18];

    const size_t SZ = (size_t)NROW * DIM;          // 4,194,304 floats
    float* slot0 = (float*)d_out;
    float* slot1 = slot0 + (size_t)NROW * SS;

    float* x    = slot0;
    float* attn = slot0 + SZ;
    float* ctx  = slot0 + 2 * SZ;
    float* xn   = slot0 + 3 * SZ;
    float* q    = slot1;
    float* kbuf = slot1 + SZ;
    float* vbuf = slot1 + 2 * SZ;
    float* gate = slot1 + 3 * SZ;
    float* h1    = slot0;                      // 8192x1024
    float* wf2f  = slot1;                      // GPx2048
    float* w2pad = slot1 + SZ;                 // 1024xGP
    float* Wp    = slot0 + 2 * SZ;             // 4 partials 1024x2048 (8M = 2SZ)
    float* Wf    = Wp;                         // reduced in place
    float* cvec  = slot0 + 3 * SZ;             // 2048 (after add4)
    float* scores = slot1;
    float* sdr    = slot0;

    dim3 blk(256);
    dim3 g512(4, 64);                         // 128x128 tiles, N=512
    dim3 gGelu(8, 32);                        // big: 256x128 tiles, N=1024
    dim3 gWs(16, 8, 4);                       // W split-K x4
    dim3 gSC(16, 32);                         // big: 256x128 tiles, N=2048

    k_embed_ln<<<NROW, blk, 0, stream>>>(tokens, table, ln_g, ln_b, x, xn);
    k_gemm_f32<EPI_BIAS>     <<<g512,  blk, 0, stream>>>(xn, wq, bq, q,    NROW, DIM, DIM, nullptr, nullptr);
    k_gemm_f32<EPI_BIAS>     <<<g512,  blk, 0, stream>>>(xn, wk, bk, kbuf, NROW, DIM, DIM, nullptr, nullptr);
    k_gemm_f32<EPI_BIAS>     <<<g512,  blk, 0, stream>>>(xn, wv, bv, vbuf, NROW, DIM, DIM, nullptr, nullptr);
    k_gemm_f32<EPI_SIGMOID>  <<<g512,  blk, 0, stream>>>(xn, wg, bg, gate, NROW, DIM, DIM, nullptr, nullptr);
    k_attn                   <<<NROW,  blk, 0, stream>>>(q, kbuf, vbuf, attn);
    k_gemm_f32<EPI_GATERES>  <<<g512,  blk, 0, stream>>>(attn, wo, bo, ctx, NROW, DIM, DIM, x, gate);
    k_gemm_f32_big<EPI_GELU> <<<gGelu, blk, 0, stream>>>(ctx, w1, b1, h1,   NROW, 2 * DIM, DIM);
    k_conv_wf                <<<GP,    blk, 0, stream>>>(wf, wf2f);
    k_pad_w2                 <<<(1024 * GP + 255) / 256, blk, 0, stream>>>(w2, w2pad);
    k_gemm_f32<EPI_NONE, 512><<<gWs,   blk, 0, stream>>>(w2pad, wf2f, nullptr, Wp, 1024, SS, GP, nullptr, nullptr);
    k_add4                   <<<2048,  blk, 0, stream>>>((float4*)Wp, 524288);
    k_bias_c                 <<<SS/4,  blk, 0, stream>>>(b2, wf2f, cvec);
    k_gemm_f32_big<EPI_BIAS> <<<gSC,   blk, 0, stream>>>(h1, Wf, cvec, scores, NROW, SS, 2 * DIM);
    k_topk                   <<<NROW,  blk, 0, stream>>>(scores, sdr);
}

// Round 11
// 1320.263 us; speedup vs baseline: 2.6951x; 1.1398x over previous
//
#include <hip/hip_runtime.h>
#include <math.h>

// Problem constants
#define NROW 8192   // B*T
#define DIM  512
#define TT   2048
#define HH   4
#define DH   128
#define GG   2025   // GH*GW
#define GP   2032   // GG padded to %16
#define SS   2048
#define KTOP 40

// ---------------------------------------------------------------------------
// embed gather + layernorm:  x = table[tok], xn = LN(x)*g + b
// ---------------------------------------------------------------------------
__global__ __launch_bounds__(256) void k_embed_ln(
    const int* __restrict__ tokens, const float* __restrict__ table,
    const float* __restrict__ g, const float* __restrict__ b,
    float* __restrict__ x, float* __restrict__ xn)
{
    __shared__ float red[4];
    const int row = blockIdx.x;
    const int tid = threadIdx.x;
    const float* src = table + (size_t)tokens[row] * DIM;
    float v0 = src[tid], v1 = src[tid + 256];

    float s = v0 + v1;
    for (int off = 32; off; off >>= 1) s += __shfl_xor(s, off, 64);
    if ((tid & 63) == 0) red[tid >> 6] = s;
    __syncthreads();
    float mean = (red[0] + red[1] + red[2] + red[3]) * (1.0f / 512.0f);
    __syncthreads();

    float d0 = v0 - mean, d1 = v1 - mean;
    float ss = d0 * d0 + d1 * d1;
    for (int off = 32; off; off >>= 1) ss += __shfl_xor(ss, off, 64);
    if ((tid & 63) == 0) red[tid >> 6] = ss;
    __syncthreads();
    float var = (red[0] + red[1] + red[2] + red[3]) * (1.0f / 512.0f);
    float rs = 1.0f / sqrtf(var + 1e-5f);

    size_t base = (size_t)row * DIM;
    x[base + tid]        = v0;
    x[base + tid + 256]  = v1;
    xn[base + tid]       = d0 * rs * g[tid] + b[tid];
    xn[base + tid + 256] = d1 * rs * g[tid + 256] + b[tid + 256];
}

// ---------------------------------------------------------------------------
// f32 GEMM  C = epi(A @ B + bias). A: MxK, B: KxN row-major.
// 128x128 tile, BK=16, 256 thr, 8x8/thread. (proven rounds 4/6/7)
// KCH>0: split-K partials to C + z*M*N, no epilogue (proven round 10).
// EPI_QKVG: bias then sigmoid only for columns n>=1536 (gate block).
// EPI_GATERES: gate read with row stride gstride (packed-QKVG support).
// ---------------------------------------------------------------------------
enum { EPI_BIAS = 0, EPI_SIGMOID = 1, EPI_GATERES = 2, EPI_GELU = 3, EPI_NONE = 4, EPI_QKVG = 5 };

template<int EPI, int KCH = 0>
__global__ __launch_bounds__(256) void k_gemm_f32(
    const float* __restrict__ A, const float* __restrict__ B,
    const float* __restrict__ bias, float* __restrict__ C,
    int M, int N, int K,
    const float* __restrict__ resid, const float* __restrict__ gate, int gstride)
{
    __shared__ float As[16][132];   // [k][m]
    __shared__ float Bs[16][132];   // [k][n]
    const int tid = threadIdx.x;
    const int tx = tid & 15, ty = tid >> 4;
    const int bm = blockIdx.y * 128, bn = blockIdx.x * 128;
    float acc[8][8] = {};

    int kbeg = 0, kend = K;
    float* Cw = C;
    if (KCH > 0) {
        kbeg = blockIdx.z * KCH;
        kend = min(kbeg + KCH, K);
        Cw = C + (size_t)blockIdx.z * M * N;
    }

    const int a_m = tid >> 2;
    const int a_c = (tid & 3) * 4;
    const int b_r = tid >> 5;
    const int b_n = (tid & 31) * 4;

    const float* Arow0 = A + (size_t)(bm + a_m) * K + a_c;
    const float* Arow1 = A + (size_t)(bm + a_m + 64) * K + a_c;
    const float* Brow0 = B + (size_t)b_r * N + bn + b_n;
    const float* Brow1 = B + (size_t)(b_r + 8) * N + bn + b_n;

    for (int k0 = kbeg; k0 < kend; k0 += 16) {
        float4 av0 = *(const float4*)(Arow0 + k0);
        float4 av1 = *(const float4*)(Arow1 + k0);
        float4 bv0 = *(const float4*)(Brow0 + (size_t)k0 * N);
        float4 bv1 = *(const float4*)(Brow1 + (size_t)k0 * N);
        __syncthreads();
        As[a_c + 0][a_m] = av0.x; As[a_c + 1][a_m] = av0.y;
        As[a_c + 2][a_m] = av0.z; As[a_c + 3][a_m] = av0.w;
        As[a_c + 0][a_m + 64] = av1.x; As[a_c + 1][a_m + 64] = av1.y;
        As[a_c + 2][a_m + 64] = av1.z; As[a_c + 3][a_m + 64] = av1.w;
        *(float4*)&Bs[b_r][b_n]     = bv0;
        *(float4*)&Bs[b_r + 8][b_n] = bv1;
        __syncthreads();
#pragma unroll
        for (int kk = 0; kk < 16; ++kk) {
            float4 a0 = *(const float4*)&As[kk][ty * 4];
            float4 a1 = *(const float4*)&As[kk][64 + ty * 4];
            float4 b0 = *(const float4*)&Bs[kk][tx * 4];
            float4 b1 = *(const float4*)&Bs[kk][64 + tx * 4];
            float av[8] = {a0.x, a0.y, a0.z, a0.w, a1.x, a1.y, a1.z, a1.w};
            float bv[8] = {b0.x, b0.y, b0.z, b0.w, b1.x, b1.y, b1.z, b1.w};
#pragma unroll
            for (int i = 0; i < 8; ++i)
#pragma unroll
                for (int j = 0; j < 8; ++j)
                    acc[i][j] = fmaf(av[i], bv[j], acc[i][j]);
        }
    }

#pragma unroll
    for (int i = 0; i < 8; ++i) {
        int m = bm + 4 * ty + (i & 3) + (i >> 2) * 64;
#pragma unroll
        for (int half = 0; half < 2; ++half) {
            int n0 = bn + 4 * tx + half * 64;
            size_t idx = (size_t)m * N + n0;
            float4 o;
            float* oo = (float*)&o;
#pragma unroll
            for (int j = 0; j < 4; ++j) {
                float t = acc[i][half * 4 + j];
                if (EPI != EPI_NONE && KCH == 0) t += bias[n0 + j];
                float r;
                if (KCH > 0)                 r = t;
                else if (EPI == EPI_SIGMOID) r = 1.0f / (1.0f + expf(-t));
                else if (EPI == EPI_QKVG)    r = (n0 + j >= 1536) ? 1.0f / (1.0f + expf(-t)) : t;
                else if (EPI == EPI_GATERES) r = resid[idx + j] + gate[(size_t)m * gstride + n0 + j] * t;
                else if (EPI == EPI_GELU)    r = 0.5f * t * (1.0f + erff(t * 0.70710678118654752440f));
                else                         r = t;
                oo[j] = r;
            }
            *(float4*)&Cw[idx] = o;
        }
    }
}

// Wf[i] = p0+p1+p2+p3 (float4-wide), in place over p0  (proven round 10)
__global__ __launch_bounds__(256) void k_add4(float4* __restrict__ p, int n4)
{
    const int i = blockIdx.x * 256 + threadIdx.x;
    if (i >= n4) return;
    float4 a = p[i], b = p[i + n4], c = p[i + 2 * n4], d = p[i + 3 * n4];
    a.x += b.x + c.x + d.x; a.y += b.y + c.y + d.y;
    a.z += b.z + c.z + d.z; a.w += b.w + c.w + d.w;
    p[i] = a;
}

// ---------------------------------------------------------------------------
// pack wq|wk|wv|wg -> wpack (512x2048) and biases -> bpack (2048)
// ---------------------------------------------------------------------------
__global__ __launch_bounds__(256) void k_pack_qkvg(
    const float* __restrict__ wq, const float* __restrict__ wk,
    const float* __restrict__ wv, const float* __restrict__ wg,
    const float* __restrict__ bq, const float* __restrict__ bk,
    const float* __restrict__ bv, const float* __restrict__ bg,
    float* __restrict__ wpack, float* __restrict__ bpack)
{
    const int idx = blockIdx.x * 256 + threadIdx.x;   // 512*2048
    const int k = idx >> 11, n = idx & 2047;
    const int sel = n >> 9, nn = n & 511;
    const float* w = (sel == 0) ? wq : (sel == 1) ? wk : (sel == 2) ? wv : wg;
    wpack[idx] = w[(size_t)k * 512 + nn];
    if (idx < 2048) {
        const float* bb = (sel == 0) ? bq : (sel == 1) ? bk : (sel == 2) ? bv : bg;
        bpack[idx] = bb[nn];
    }
}

// ---------------------------------------------------------------------------
// banded attention over packed QKVG (row stride 2048; q@0,k@512,v@1024).
// window half-width 5 (W=11). One wave per (b,t,h). out: 8192x512.
// ---------------------------------------------------------------------------
__global__ __launch_bounds__(256) void k_attn(
    const float* __restrict__ qkvg, float* __restrict__ out)
{
    const int w    = (blockIdx.x << 2) + (threadIdx.x >> 6);
    const int lane = threadIdx.x & 63;
    const int h = w & 3;
    const int t = (w >> 2) & 2047;
    const int b = w >> 13;
    const size_t qb = ((size_t)(b * TT + t)) * 2048 + h * DH;
    const float q0 = qkvg[qb + lane], q1 = qkvg[qb + 64 + lane];

    float s[11];
#pragma unroll
    for (int o = 0; o < 11; ++o) {
        int pos = t + o - 5;
        bool valid = (pos >= 0 && pos < TT);
        float p = 0.0f;
        if (valid) {
            size_t kb = ((size_t)(b * TT + pos)) * 2048 + 512 + h * DH;
            p = q0 * qkvg[kb + lane] + q1 * qkvg[kb + 64 + lane];
        }
        for (int off = 32; off; off >>= 1) p += __shfl_xor(p, off, 64);
        s[o] = valid ? p / sqrtf(128.0f) : -1e9f;
    }
    float m = s[0];
#pragma unroll
    for (int o = 1; o < 11; ++o) m = fmaxf(m, s[o]);
    float e[11], sum = 0.0f;
#pragma unroll
    for (int o = 0; o < 11; ++o) { e[o] = expf(s[o] - m); sum += e[o]; }

    float o0 = 0.0f, o1 = 0.0f;
#pragma unroll
    for (int o = 0; o < 11; ++o) {
        int pos = t + o - 5;
        if (pos < 0 || pos >= TT) continue;
        float a = e[o] / sum;
        size_t vb = ((size_t)(b * TT + pos)) * 2048 + 1024 + h * DH;
        o0 = fmaf(a, qkvg[vb + lane], o0);
        o1 = fmaf(a, qkvg[vb + 64 + lane], o1);
    }
    const size_t ob = ((size_t)(b * TT + t)) * DIM + h * DH;
    out[ob + lane]      = o0;
    out[ob + 64 + lane] = o1;
}

// ---------------------------------------------------------------------------
// wf2f[q,s] = sum_p L[q,p] * wf[p,s]  (f64 accumulate, f32 out; GP rows)
// ---------------------------------------------------------------------------
__global__ __launch_bounds__(256) void k_conv_wf(
    const float* __restrict__ wf, float* __restrict__ wf2f)
{
    __shared__ float w[25];
    const int qq = blockIdx.x;
    if (qq >= GG) {
        for (int s = threadIdx.x; s < SS; s += 256)
            wf2f[(size_t)qq * SS + s] = 0.0f;
        return;
    }
    const int y = qq / 45, x = qq % 45;
    if (threadIdx.x < 25) {
        int ki = threadIdx.x / 5, kj = threadIdx.x % 5;
        double gi = exp(-0.5 * (double)((ki - 2) * (ki - 2)));
        double gj = exp(-0.5 * (double)((kj - 2) * (kj - 2)));
        double Z  = 1.0 + 2.0 * exp(-0.5) + 2.0 * exp(-2.0);
        w[threadIdx.x] = (float)(gi * gj / (Z * Z));
    }
    __syncthreads();
    for (int s = threadIdx.x; s < SS; s += 256) {
        double acc = 0.0;
#pragma unroll
        for (int dy = -2; dy <= 2; ++dy) {
            int yy = y + dy;
            if (yy < 0 || yy >= 45) continue;
#pragma unroll
            for (int dx = -2; dx <= 2; ++dx) {
                int xx2 = x + dx;
                if (xx2 < 0 || xx2 >= 45) continue;
                acc = fma((double)w[(dy + 2) * 5 + (dx + 2)],
                          (double)wf[(size_t)(yy * 45 + xx2) * SS + s], acc);
            }
        }
        wf2f[(size_t)qq * SS + s] = (float)acc;
    }
}

// w2pad[m][p] = p < GG ? w2[m][p] : 0   (1024 x GP)
__global__ __launch_bounds__(256) void k_pad_w2(
    const float* __restrict__ w2, float* __restrict__ w2pad)
{
    const size_t idx = (size_t)blockIdx.x * 256 + threadIdx.x;
    if (idx >= (size_t)1024 * GP) return;
    const int m = (int)(idx / GP), p = (int)(idx % GP);
    w2pad[idx] = (p < GG) ? w2[(size_t)m * GG + p] : 0.0f;
}

// c[s] = sum_q b2[q] * wf2f[q,s]  (f64 accumulate, f32 out)
__global__ __launch_bounds__(256) void k_bias_c(
    const float* __restrict__ b2, const float* __restrict__ wf2f,
    float* __restrict__ c)
{
    const int s = blockIdx.x * 4 + (threadIdx.x >> 6);
    const int lane = threadIdx.x & 63;
    double acc = 0.0;
    for (int qq = lane; qq < GG; qq += 64)
        acc = fma((double)b2[qq], (double)wf2f[(size_t)qq * SS + s], acc);
    for (int off = 32; off; off >>= 1) acc += __shfl_xor(acc, off, 64);
    if (lane == 0) c[s] = (float)acc;
}

// ---------------------------------------------------------------------------
// top-40 one-hot per row of 2048; iterative argmax, tie -> lower index
// ---------------------------------------------------------------------------
__global__ __launch_bounds__(256) void k_topk(
    const float* __restrict__ scores, float* __restrict__ sdr)
{
    __shared__ float vals[SS];
    __shared__ float rv[4];
    __shared__ int   ri[4];
    const int row = blockIdx.x;
    const float* srow = scores + (size_t)row * SS;
    float* drow = sdr + (size_t)row * SS;
    for (int i = threadIdx.x; i < SS; i += 256) { vals[i] = srow[i]; drow[i] = 0.0f; }
    __syncthreads();
    const int lane = threadIdx.x & 63, wid = threadIdx.x >> 6;
    for (int it = 0; it < KTOP; ++it) {
        float bv = -INFINITY; int bi = 0x7fffffff;
        for (int i = threadIdx.x; i < SS; i += 256) {
            float vv = vals[i];
            if (vv > bv) { bv = vv; bi = i; }
        }
        for (int off = 32; off; off >>= 1) {
            float ov = __shfl_xor(bv, off, 64);
            int   oi = __shfl_xor(bi, off, 64);
            if (ov > bv || (ov == bv && oi < bi)) { bv = ov; bi = oi; }
        }
        if (lane == 0) { rv[wid] = bv; ri[wid] = bi; }
        __syncthreads();
        if (threadIdx.x == 0) {
            float fv = rv[0]; int fi = ri[0];
            for (int wdx = 1; wdx < 4; ++wdx)
                if (rv[wdx] > fv || (rv[wdx] == fv && ri[wdx] < fi)) { fv = rv[wdx]; fi = ri[wdx]; }
            vals[fi] = -INFINITY;
            drow[fi] = 1.0f;
        }
        __syncthreads();
    }
}

// ---------------------------------------------------------------------------
// Buffer plan (all inside d_out; slot0/slot1 = 16,777,216 floats each):
//  1 embed_ln -> x@s0+0, xn@s0+3SZ
//  2 pack_qkvg -> wpack@s0+SZ (1M), bpack@s0+SZ+1M (2048)
//  3 QKVG GEMM (xn @ wpack) -> qkvg@s1 (8192x2048 = whole slot1)
//  4 attn(qkvg) -> attn@s0+SZ (over dead wpack/bpack)
//  5 gateres (attn@wo; resid=x, gate=qkvg+1536 stride 2048) -> ctx@s0+2SZ
//  6 gelu -> h1@s0[0..2SZ) (x, attn dead)
//  7 conv_wf -> wf2f@s1 (qkvg dead); 8 pad_w2 -> w2pad@s1+SZ
//  9 W splitK x4 -> Wp@s0[2SZ..4SZ) (ctx, xn dead)
// 10 add4 -> Wf@s0+2SZ
// 11 bias_c -> cvec@s0+3SZ
// 12 scores GEMM (h1, Wf, cvec all s0) -> scores@s1
// 13 topk -> sdr@s0
// ---------------------------------------------------------------------------
extern "C" void kernel_launch(void* const* d_in, const int* in_sizes, int n_in,
                              void* d_out, int out_size, void* d_ws, size_t ws_size,
                              hipStream_t stream)
{
    (void)d_ws; (void)ws_size; (void)in_sizes; (void)n_in; (void)out_size;

    const int*   tokens = (const int*)d_in[0];
    const float* table  = (const float*)d_in[1];
    const float* ln_g   = (const float*)d_in[2];
    const float* ln_b   = (const float*)d_in[3];
    const float* wq = (const float*)d_in[4];  const float* bq = (const float*)d_in[5];
    const float* wk = (const float*)d_in[6];  const float* bk = (const float*)d_in[7];
    const float* wv = (const float*)d_in[8];  const float* bv = (const float*)d_in[9];
    const float* wo = (const float*)d_in[10]; const float* bo = (const float*)d_in[11];
    const float* wg = (const float*)d_in[12]; const float* bg = (const float*)d_in[13];
    const float* w1 = (const float*)d_in[14]; const float* b1 = (const float*)d_in[15];
    const float* w2 = (const float*)d_in[16]; const float* b2 = (const float*)d_in[17];
    const float* wf = (const float*)d_in[18];

    const size_t SZ = (size_t)NROW * DIM;          // 4,194,304 floats
    const size_t MEG = 1u << 20;
    float* slot0 = (float*)d_out;
    float* slot1 = slot0 + (size_t)NROW * SS;

    float* x     = slot0;
    float* wpack = slot0 + SZ;                 // 512x2048
    float* bpack = slot0 + SZ + MEG;           // 2048
    float* attn  = slot0 + SZ;                 // after QKVG GEMM (wpack dead)
    float* ctx   = slot0 + 2 * SZ;
    float* xn    = slot0 + 3 * SZ;
    float* qkvg  = slot1;                      // 8192x2048
    float* h1    = slot0;                      // 8192x1024
    float* wf2f  = slot1;                      // GPx2048
    float* w2pad = slot1 + SZ;                 // 1024xGP
    float* Wp    = slot0 + 2 * SZ;             // 4 partials 1024x2048 (= 2SZ)
    float* Wf    = Wp;                         // reduced in place
    float* cvec  = slot0 + 3 * SZ;             // 2048
    float* scores = slot1;
    float* sdr    = slot0;

    dim3 blk(256);
    dim3 gQKVG(16, 64);                       // N=2048
    dim3 g512(4, 64);                         // N=512
    dim3 gGelu(8, 64);                        // N=1024
    dim3 gWs(16, 8, 4);                       // W split-K x4
    dim3 gSC(16, 64);                         // N=2048

    k_embed_ln<<<NROW, blk, 0, stream>>>(tokens, table, ln_g, ln_b, x, xn);
    k_pack_qkvg<<<4096, blk, 0, stream>>>(wq, wk, wv, wg, bq, bk, bv, bg, wpack, bpack);
    k_gemm_f32<EPI_QKVG>     <<<gQKVG, blk, 0, stream>>>(xn, wpack, bpack, qkvg, NROW, 2048, DIM, nullptr, nullptr, 0);
    k_attn                   <<<NROW,  blk, 0, stream>>>(qkvg, attn);
    k_gemm_f32<EPI_GATERES>  <<<g512,  blk, 0, stream>>>(attn, wo, bo, ctx, NROW, DIM, DIM, x, qkvg + 1536, 2048);
    k_gemm_f32<EPI_GELU>     <<<gGelu, blk, 0, stream>>>(ctx, w1, b1, h1, NROW, 2 * DIM, DIM, nullptr, nullptr, 0);
    k_conv_wf                <<<GP,    blk, 0, stream>>>(wf, wf2f);
    k_pad_w2                 <<<(1024 * GP + 255) / 256, blk, 0, stream>>>(w2, w2pad);
    k_gemm_f32<EPI_NONE, 512><<<gWs,   blk, 0, stream>>>(w2pad, wf2f, nullptr, Wp, 1024, SS, GP, nullptr, nullptr, 0);
    k_add4                   <<<2048,  blk, 0, stream>>>((float4*)Wp, 524288);
    k_bias_c                 <<<SS/4,  blk, 0, stream>>>(b2, wf2f, cvec);
    k_gemm_f32<EPI_BIAS>     <<<gSC,   blk, 0, stream>>>(h1, Wf, cvec, scores, NROW, SS, 2 * DIM, nullptr, nullptr, 0);
    k_topk                   <<<NROW,  blk, 0, stream>>>(scores, sdr);
}